// Round 7
// baseline (1329.206 us; speedup 1.0000x reference)
//
#include <hip/hip_runtime.h>

#define NCSR 15
#define MAXP 6
#define MAXT 8
#define NPT 21
#define NWT 37

typedef __attribute__((ext_vector_type(8))) short bfrag;
typedef __attribute__((ext_vector_type(4))) float ffrag;

__device__ __forceinline__ float b2f(unsigned short s) {
  return __uint_as_float(((unsigned int)s) << 16);
}
__device__ __forceinline__ unsigned short f2b(float f) {
  unsigned int u = __float_as_uint(f);
  u = (u + 0x7FFFu + ((u >> 16) & 1u)) >> 16;
  return (unsigned short)u;
}
__device__ __forceinline__ float ldf(const void* p, size_t i, int bf) {
  if (bf) return b2f(((const unsigned short*)p)[i]);
  return ((const float*)p)[i];
}

struct CsrDesc {
  const int* src; const int* dst; int E; int n_dst;
  int* rowptr; unsigned short* csrc; int* slot; int pad;
};
struct CsrArgs { CsrDesc d[NCSR]; };

struct PTask { const void* src; float* dst; int n; int pad; };
struct PArgs { PTask t[NPT]; };

struct WTask { const void* src; unsigned short* dst; int K; int N; int eoff; int pad; };
struct WArgs { WTask t[NWT]; };

struct MPass { const unsigned short* A; const unsigned short* W; const float* bias; int lda; int ldw; int flags; };
struct MTask {
  MPass p[MAXP];
  const unsigned short* R; unsigned short* C;
  int npass, n, K, ldc, relu, pad;
};
struct MArgs { MTask t[MAXT]; };

struct GTask { const int* rowptr; const unsigned short* csrc; const unsigned short* X; unsigned short* out; int n_dst; int ldx; int mode; int pad; };
struct GArgs { GTask t[MAXT]; };

struct ETask { const void* A; const unsigned short* W; const float* bias; unsigned short* C; int n, K, ldc, pad; };
struct EArgs { ETask t[3]; };

struct BTask { const void* w; const float* b; unsigned short* out; int n; int pad[3]; };
struct BArgs { BTask t[4]; };

__global__ void k_flag(const unsigned int* probe, int* flag) {
  if (threadIdx.x == 0) *flag = (probe[0] == 0x3F800000u) ? 0 : 1;
}

__global__ void k_cv_params(PArgs args, const int* __restrict__ flagp) {
  const int bf = *flagp;
  const PTask T = args.t[blockIdx.y];
  for (int i = blockIdx.x * blockDim.x + threadIdx.x; i < T.n; i += gridDim.x * blockDim.x)
    T.dst[i] = ldf(T.src, (size_t)i, bf);
}

__global__ void k_cv_wt(WArgs args, const int* __restrict__ flagp) {
  const int bf = *flagp;
  const WTask T = args.t[blockIdx.y];
  const int total = T.K * T.N;
  const size_t eoff = (size_t)T.eoff;
  for (int i = blockIdx.x * blockDim.x + threadIdx.x; i < total; i += gridDim.x * blockDim.x) {
    int n = i / T.K, k = i - n * T.K;
    T.dst[i] = f2b(ldf(T.src, eoff + (size_t)k * T.N + n, bf));
  }
}

__global__ void k_biasrelu_multi(BArgs args, const int* __restrict__ flagp) {
  const int bf = *flagp;
  const BTask T = args.t[blockIdx.y];
  for (int i = blockIdx.x * blockDim.x + threadIdx.x; i < T.n; i += gridDim.x * blockDim.x) {
    float v = ldf(T.w, (size_t)i, bf) + T.b[i & 127];
    T.out[i] = f2b(v > 0.f ? v : 0.f);
  }
}

// count pass: returned old value IS the edge's slot within its dst row
__global__ void k_csr_count(CsrArgs args) {
  const CsrDesc cd = args.d[blockIdx.y];
  for (int e = blockIdx.x * blockDim.x + threadIdx.x; e < cd.E; e += gridDim.x * blockDim.x)
    cd.slot[e] = atomicAdd(&cd.rowptr[cd.dst[e] + 1], 1);
}

__global__ void k_csr_scan(CsrArgs args) {
  const CsrDesc cd = args.d[blockIdx.x];
  const int n = cd.n_dst + 1;
  const int t = threadIdx.x;
  const int lane = t & 63, w = t >> 6;
  __shared__ int wsum[16];
  int carry = 0;
  for (int base = 0; base < n; base += 1024) {
    int i = base + t;
    int v = (i < n) ? cd.rowptr[i] : 0;
    for (int off = 1; off < 64; off <<= 1) {
      int u = __shfl_up(v, off, 64);
      if (lane >= off) v += u;
    }
    if (lane == 63) wsum[w] = v;
    __syncthreads();
    if (w == 0) {
      int s = (lane < 16) ? wsum[lane] : 0;
      for (int off = 1; off < 16; off <<= 1) {
        int u = __shfl_up(s, off, 64);
        if (lane >= off) s += u;
      }
      if (lane < 16) wsum[lane] = s;
    }
    __syncthreads();
    int nv = v + carry + (w > 0 ? wsum[w - 1] : 0);
    if (i < n) cd.rowptr[i] = nv;
    carry += wsum[15];
    __syncthreads();
  }
}

// fill: deterministic placement, no atomics; csrc ushort (all src counts < 65536)
__global__ void k_csr_fill(CsrArgs args) {
  const CsrDesc cd = args.d[blockIdx.y];
  for (int e = blockIdx.x * blockDim.x + threadIdx.x; e < cd.E; e += gridDim.x * blockDim.x) {
    int d = cd.dst[e];
    cd.csrc[cd.rowptr[d] + cd.slot[e]] = (unsigned short)cd.src[e];
  }
}

// one wave per dst row; lane = one uint = 2 bf16 cols; 4-edge unroll for MLP
__global__ void k_gather_multi(GArgs args) {
  const GTask T = args.t[blockIdx.y];
  int w = (blockIdx.x * blockDim.x + threadIdx.x) >> 6;
  if (w >= T.n_dst) return;
  int lane = threadIdx.x & 63;
  int beg = T.rowptr[w], end = T.rowptr[w + 1];
  float a0 = 0.f, a1 = 0.f;
  int j = beg;
  if (T.mode == 0) {
    for (; j + 3 < end; j += 4) {
      unsigned int u0 = ((const unsigned int*)(T.X + (size_t)T.csrc[j] * T.ldx))[lane];
      unsigned int u1 = ((const unsigned int*)(T.X + (size_t)T.csrc[j + 1] * T.ldx))[lane];
      unsigned int u2 = ((const unsigned int*)(T.X + (size_t)T.csrc[j + 2] * T.ldx))[lane];
      unsigned int u3 = ((const unsigned int*)(T.X + (size_t)T.csrc[j + 3] * T.ldx))[lane];
      a0 += __uint_as_float(u0 << 16) + __uint_as_float(u1 << 16)
          + __uint_as_float(u2 << 16) + __uint_as_float(u3 << 16);
      a1 += __uint_as_float(u0 & 0xFFFF0000u) + __uint_as_float(u1 & 0xFFFF0000u)
          + __uint_as_float(u2 & 0xFFFF0000u) + __uint_as_float(u3 & 0xFFFF0000u);
    }
    for (; j < end; ++j) {
      unsigned int u0 = ((const unsigned int*)(T.X + (size_t)T.csrc[j] * T.ldx))[lane];
      a0 += __uint_as_float(u0 << 16);
      a1 += __uint_as_float(u0 & 0xFFFF0000u);
    }
  } else {
    for (; j + 3 < end; j += 4) {
      unsigned int u0 = ((const unsigned int*)(T.X + (size_t)T.csrc[j] * T.ldx))[lane];
      unsigned int u1 = ((const unsigned int*)(T.X + (size_t)T.csrc[j + 1] * T.ldx))[lane];
      unsigned int u2 = ((const unsigned int*)(T.X + (size_t)T.csrc[j + 2] * T.ldx))[lane];
      unsigned int u3 = ((const unsigned int*)(T.X + (size_t)T.csrc[j + 3] * T.ldx))[lane];
      a0 = fmaxf(fmaxf(a0, fmaxf(__uint_as_float(u0 << 16), __uint_as_float(u1 << 16))),
                 fmaxf(__uint_as_float(u2 << 16), __uint_as_float(u3 << 16)));
      a1 = fmaxf(fmaxf(a1, fmaxf(__uint_as_float(u0 & 0xFFFF0000u), __uint_as_float(u1 & 0xFFFF0000u))),
                 fmaxf(__uint_as_float(u2 & 0xFFFF0000u), __uint_as_float(u3 & 0xFFFF0000u)));
    }
    for (; j < end; ++j) {
      unsigned int u0 = ((const unsigned int*)(T.X + (size_t)T.csrc[j] * T.ldx))[lane];
      a0 = fmaxf(a0, __uint_as_float(u0 << 16));
      a1 = fmaxf(a1, __uint_as_float(u0 & 0xFFFF0000u));
    }
  }
  unsigned int* po = (unsigned int*)(T.out + (size_t)w * 128);
  po[lane] = (unsigned int)f2b(a0) | ((unsigned int)f2b(a1) << 16);
}

// MFMA multi-task group GEMM, 64-row x 128-col tile per 256-thread block
__launch_bounds__(256)
__global__ void k_mg(MArgs args) {
  const MTask* T = &args.t[blockIdx.y];
  const int n = T->n;
  const int row0 = blockIdx.x * 64;
  if (row0 >= n) return;
  __shared__ __align__(16) unsigned short As[64][40];
  __shared__ __align__(16) unsigned short Ws[128][40];
  const int t = threadIdx.x;
  const int wave = t >> 6, lane = t & 63;
  const int m16 = lane & 15, kq = lane >> 4;
  const int K = T->K;
  ffrag acc[4][2], accO[4][2];
#pragma unroll
  for (int i = 0; i < 4; ++i)
#pragma unroll
    for (int j = 0; j < 2; ++j) { acc[i][j] = (ffrag)0.f; accO[i][j] = (ffrag)0.f; }
  const int colbase = wave * 32;
  for (int ip = 0; ip < T->npass; ++ip) {
    const unsigned short* Ap = T->p[ip].A;
    const unsigned short* Wp = T->p[ip].W;
    const int lda = T->p[ip].lda, ldw = T->p[ip].ldw;
    for (int k0 = 0; k0 < K; k0 += 32) {
      __syncthreads();
      {
        int r = t >> 2, c = t & 3;
        int row = row0 + r;
        int4 v = {0, 0, 0, 0};
        if (row < n) v = *(const int4*)(Ap + (size_t)row * lda + k0 + c * 8);
        *(int4*)&As[r][c * 8] = v;
      }
#pragma unroll
      for (int e = t; e < 512; e += 256) {
        int nn = e >> 2, c = e & 3;
        *(int4*)&Ws[nn][c * 8] = *(const int4*)(Wp + (size_t)nn * ldw + k0 + c * 8);
      }
      __syncthreads();
      bfrag b0 = *(const bfrag*)&Ws[colbase + m16][kq * 8];
      bfrag b1 = *(const bfrag*)&Ws[colbase + 16 + m16][kq * 8];
#pragma unroll
      for (int rb = 0; rb < 4; ++rb) {
        bfrag a = *(const bfrag*)&As[rb * 16 + m16][kq * 8];
        acc[rb][0] = __builtin_amdgcn_mfma_f32_16x16x32_bf16(a, b0, acc[rb][0], 0, 0, 0);
        acc[rb][1] = __builtin_amdgcn_mfma_f32_16x16x32_bf16(a, b1, acc[rb][1], 0, 0, 0);
      }
    }
    if (T->p[ip].flags & 1) {
      const float* bias = T->p[ip].bias;
      float bv0 = bias ? bias[colbase + m16] : 0.f;
      float bv1 = bias ? bias[colbase + 16 + m16] : 0.f;
#pragma unroll
      for (int rb = 0; rb < 4; ++rb)
#pragma unroll
        for (int cb = 0; cb < 2; ++cb) {
          float bv = cb ? bv1 : bv0;
#pragma unroll
          for (int r = 0; r < 4; ++r) {
            float v = acc[rb][cb][r] + bv;
            if (T->relu) v = v > 0.f ? v : 0.f;
            accO[rb][cb][r] += v;
          }
          acc[rb][cb] = (ffrag)0.f;
        }
    }
  }
  const int ldc = T->ldc;
#pragma unroll
  for (int rb = 0; rb < 4; ++rb)
#pragma unroll
    for (int cb = 0; cb < 2; ++cb) {
      int col = colbase + cb * 16 + m16;
#pragma unroll
      for (int r = 0; r < 4; ++r) {
        int row = row0 + rb * 16 + kq * 4 + r;
        if (row < n) {
          float v = accO[rb][cb][r];
          if (T->R) v += b2f(T->R[(size_t)row * ldc + col]);
          T->C[(size_t)row * ldc + col] = f2b(v);
        }
      }
    }
}

// MFMA embed from raw flag-dtype A (ragged K), 64-row tile, relu+bias epilogue
__launch_bounds__(256)
__global__ void k_embed_multi(EArgs args, const int* __restrict__ flagp) {
  const ETask T = args.t[blockIdx.y];
  const int n = T.n;
  const int row0 = blockIdx.x * 64;
  if (row0 >= n) return;
  const int bf = *flagp;
  __shared__ __align__(16) unsigned short As[64][40];
  __shared__ __align__(16) unsigned short Ws[128][40];
  const int t = threadIdx.x;
  const int wave = t >> 6, lane = t & 63;
  const int m16 = lane & 15, kq = lane >> 4;
  const int K = T.K;
  ffrag acc[4][2];
#pragma unroll
  for (int i = 0; i < 4; ++i)
#pragma unroll
    for (int j = 0; j < 2; ++j) acc[i][j] = (ffrag)0.f;
  const int colbase = wave * 32;
  for (int k0 = 0; k0 < K; k0 += 32) {
    __syncthreads();
    for (int e = t; e < 2048; e += 256) {
      int r = e >> 5, kk = e & 31;
      int row = row0 + r, k = k0 + kk;
      float f = (row < n && k < K) ? ldf(T.A, (size_t)row * K + k, bf) : 0.f;
      As[r][kk] = f2b(f);
    }
#pragma unroll
    for (int e = t; e < 512; e += 256) {
      int nn = e >> 2, c = e & 3;
      int4 v = {0, 0, 0, 0};
      if (k0 + c * 8 < K) v = *(const int4*)(T.W + (size_t)nn * K + k0 + c * 8);
      *(int4*)&Ws[nn][c * 8] = v;
    }
    __syncthreads();
    bfrag b0 = *(const bfrag*)&Ws[colbase + m16][kq * 8];
    bfrag b1 = *(const bfrag*)&Ws[colbase + 16 + m16][kq * 8];
#pragma unroll
    for (int rb = 0; rb < 4; ++rb) {
      bfrag a = *(const bfrag*)&As[rb * 16 + m16][kq * 8];
      acc[rb][0] = __builtin_amdgcn_mfma_f32_16x16x32_bf16(a, b0, acc[rb][0], 0, 0, 0);
      acc[rb][1] = __builtin_amdgcn_mfma_f32_16x16x32_bf16(a, b1, acc[rb][1], 0, 0, 0);
    }
  }
#pragma unroll
  for (int rb = 0; rb < 4; ++rb)
#pragma unroll
    for (int cb = 0; cb < 2; ++cb) {
      int col = colbase + cb * 16 + m16;
      float bv = T.bias[col];
#pragma unroll
      for (int r = 0; r < 4; ++r) {
        int row = row0 + rb * 16 + kq * 4 + r;
        if (row < n) {
          float v = acc[rb][cb][r] + bv;
          T.C[(size_t)row * T.ldc + col] = f2b(v > 0.f ? v : 0.f);
        }
      }
    }
}

// MFMA GEMM with BN+relu applied to bf16 A while staging; 64-row tile; NC=64
template<int NC>
__launch_bounds__(256)
__global__ void k_gemm_bn(const unsigned short* __restrict__ A, const unsigned short* __restrict__ W,
                          const float* __restrict__ bias, const float* __restrict__ ss,
                          unsigned short* __restrict__ C, int n, int K) {
  constexpr int CB = NC / 64;  // col-16-blocks per wave
  __shared__ __align__(16) unsigned short As[64][40];
  __shared__ __align__(16) unsigned short Ws[NC][40];
  const int t = threadIdx.x;
  const int wave = t >> 6, lane = t & 63;
  const int m16 = lane & 15, kq = lane >> 4;
  const int row0 = blockIdx.x * 64;
  if (row0 >= n) return;
  ffrag acc[4][CB];
#pragma unroll
  for (int i = 0; i < 4; ++i)
#pragma unroll
    for (int j = 0; j < CB; ++j) acc[i][j] = (ffrag)0.f;
  const int colbase = wave * 16 * CB;
  for (int k0 = 0; k0 < K; k0 += 32) {
    __syncthreads();
    for (int e = t; e < 2048; e += 256) {
      int r = e >> 5, kk = e & 31;
      int row = row0 + r, k = k0 + kk;
      float val = 0.f;
      if (row < n) {
        val = fmaf(b2f(A[(size_t)row * K + k]), ss[k], ss[K + k]);
        val = val > 0.f ? val : 0.f;
      }
      As[r][kk] = f2b(val);
    }
#pragma unroll
    for (int e = t; e < NC * 4; e += 256) {
      int nn = e >> 2, c = e & 3;
      *(int4*)&Ws[nn][c * 8] = *(const int4*)(W + (size_t)nn * K + k0 + c * 8);
    }
    __syncthreads();
#pragma unroll
    for (int cb = 0; cb < CB; ++cb) {
      bfrag b = *(const bfrag*)&Ws[colbase + cb * 16 + m16][kq * 8];
#pragma unroll
      for (int rb = 0; rb < 4; ++rb) {
        bfrag a = *(const bfrag*)&As[rb * 16 + m16][kq * 8];
        acc[rb][cb] = __builtin_amdgcn_mfma_f32_16x16x32_bf16(a, b, acc[rb][cb], 0, 0, 0);
      }
    }
  }
#pragma unroll
  for (int rb = 0; rb < 4; ++rb)
#pragma unroll
    for (int cb = 0; cb < CB; ++cb) {
      int col = colbase + cb * 16 + m16;
      float bv = bias[col];
#pragma unroll
      for (int r = 0; r < 4; ++r) {
        int row = row0 + rb * 16 + kq * 4 + r;
        if (row < n) C[(size_t)row * NC + col] = f2b(acc[rb][cb][r] + bv);
      }
    }
}

// BN1 stats over implicit z1[b] = Udr[x_dr[b]] + Up[x_p[b]] (never materialized)
__global__ void k_hstat(const int* __restrict__ xdr, const int* __restrict__ xp,
                        const unsigned short* __restrict__ Udr, const unsigned short* __restrict__ Up,
                        double* __restrict__ st, int B) {
  __shared__ double sS[4][256];
  __shared__ double sQ[4][256];
  const int t = threadIdx.x;
  const int lane = t & 63, w = t >> 6;
  const int c4 = lane * 4;
  double s0 = 0, s1 = 0, s2 = 0, s3 = 0, q0 = 0, q1 = 0, q2 = 0, q3 = 0;
  const int NW = gridDim.x * 4;
  for (int r = blockIdx.x * 4 + w; r < B; r += NW) {
    int i = xdr[r], j = xp[r];
    uint2 a = *(const uint2*)(Udr + (size_t)i * 256 + c4);
    uint2 b = *(const uint2*)(Up + (size_t)j * 256 + c4);
    float v0 = b2f((unsigned short)a.x) + b2f((unsigned short)b.x);
    float v1 = b2f((unsigned short)(a.x >> 16)) + b2f((unsigned short)(b.x >> 16));
    float v2 = b2f((unsigned short)a.y) + b2f((unsigned short)b.y);
    float v3 = b2f((unsigned short)(a.y >> 16)) + b2f((unsigned short)(b.y >> 16));
    s0 += v0; s1 += v1; s2 += v2; s3 += v3;
    q0 += (double)v0 * (double)v0; q1 += (double)v1 * (double)v1;
    q2 += (double)v2 * (double)v2; q3 += (double)v3 * (double)v3;
  }
  sS[w][c4] = s0; sS[w][c4 + 1] = s1; sS[w][c4 + 2] = s2; sS[w][c4 + 3] = s3;
  sQ[w][c4] = q0; sQ[w][c4 + 1] = q1; sQ[w][c4 + 2] = q2; sQ[w][c4 + 3] = q3;
  __syncthreads();
  double ts = sS[0][t] + sS[1][t] + sS[2][t] + sS[3][t];
  double tq = sQ[0][t] + sQ[1][t] + sQ[2][t] + sQ[3][t];
  atomicAdd(&st[t], ts);
  atomicAdd(&st[256 + t], tq);
}

// MLP layer 2: A gathered on the fly (z1 never materialized), BN1+relu inline; 64-row tile
__launch_bounds__(256)
__global__ void k_gemm_bn1(const int* __restrict__ xdr, const int* __restrict__ xp,
                           const unsigned short* __restrict__ Udr, const unsigned short* __restrict__ Up,
                           const unsigned short* __restrict__ W, const float* __restrict__ bias,
                           const float* __restrict__ ss, unsigned short* __restrict__ Co, int n) {
  __shared__ __align__(16) unsigned short As[64][40];
  __shared__ __align__(16) unsigned short Ws[128][40];
  __shared__ int gi[64], gj[64];
  const int t = threadIdx.x;
  const int wave = t >> 6, lane = t & 63;
  const int m16 = lane & 15, kq = lane >> 4;
  const int row0 = blockIdx.x * 64;
  if (row0 >= n) return;
  if (t < 64) {
    int row = row0 + t; if (row >= n) row = n - 1;
    gi[t] = xdr[row]; gj[t] = xp[row];
  }
  ffrag acc[4][2];
#pragma unroll
  for (int i = 0; i < 4; ++i)
#pragma unroll
    for (int j = 0; j < 2; ++j) acc[i][j] = (ffrag)0.f;
  const int colbase = wave * 32;
  __syncthreads();
  for (int k0 = 0; k0 < 256; k0 += 32) {
    __syncthreads();
#pragma unroll
    for (int e = t; e < 512; e += 256) {
      int r = e >> 3, seg = e & 7;
      int k = k0 + seg * 4;
      uint2 a = *(const uint2*)(Udr + (size_t)gi[r] * 256 + k);
      uint2 b = *(const uint2*)(Up + (size_t)gj[r] * 256 + k);
      float v0 = b2f((unsigned short)a.x) + b2f((unsigned short)b.x);
      float v1 = b2f((unsigned short)(a.x >> 16)) + b2f((unsigned short)(b.x >> 16));
      float v2 = b2f((unsigned short)a.y) + b2f((unsigned short)b.y);
      float v3 = b2f((unsigned short)(a.y >> 16)) + b2f((unsigned short)(b.y >> 16));
      v0 = fmaf(v0, ss[k], ss[256 + k]);         v0 = v0 > 0.f ? v0 : 0.f;
      v1 = fmaf(v1, ss[k + 1], ss[257 + k]);     v1 = v1 > 0.f ? v1 : 0.f;
      v2 = fmaf(v2, ss[k + 2], ss[258 + k]);     v2 = v2 > 0.f ? v2 : 0.f;
      v3 = fmaf(v3, ss[k + 3], ss[259 + k]);     v3 = v3 > 0.f ? v3 : 0.f;
      uint2 pk;
      pk.x = (unsigned int)f2b(v0) | ((unsigned int)f2b(v1) << 16);
      pk.y = (unsigned int)f2b(v2) | ((unsigned int)f2b(v3) << 16);
      *(uint2*)&As[r][seg * 4] = pk;
    }
#pragma unroll
    for (int e = t; e < 512; e += 256) {
      int nn = e >> 2, c = e & 3;
      *(int4*)&Ws[nn][c * 8] = *(const int4*)(W + (size_t)nn * 256 + k0 + c * 8);
    }
    __syncthreads();
    bfrag b0 = *(const bfrag*)&Ws[colbase + m16][kq * 8];
    bfrag b1 = *(const bfrag*)&Ws[colbase + 16 + m16][kq * 8];
#pragma unroll
    for (int rb = 0; rb < 4; ++rb) {
      bfrag a = *(const bfrag*)&As[rb * 16 + m16][kq * 8];
      acc[rb][0] = __builtin_amdgcn_mfma_f32_16x16x32_bf16(a, b0, acc[rb][0], 0, 0, 0);
      acc[rb][1] = __builtin_amdgcn_mfma_f32_16x16x32_bf16(a, b1, acc[rb][1], 0, 0, 0);
    }
  }
#pragma unroll
  for (int rb = 0; rb < 4; ++rb)
#pragma unroll
    for (int cb = 0; cb < 2; ++cb) {
      int col = colbase + cb * 16 + m16;
      float bv = bias[col];
#pragma unroll
      for (int r = 0; r < 4; ++r) {
        int row = row0 + rb * 16 + kq * 4 + r;
        if (row < n) Co[(size_t)row * 128 + col] = f2b(acc[rb][cb][r] + bv);
      }
    }
}

// wave-per-row column stats for bf16 matrix Z[B][C], C in {128, 64}
template<int C>
__global__ void k_bnst(const unsigned short* __restrict__ Z, int B, double* __restrict__ st) {
  constexpr int CPL = C / 64;
  __shared__ double sS[4][C];
  __shared__ double sQ[4][C];
  const int t = threadIdx.x;
  const int lane = t & 63, w = t >> 6;
  double s[CPL] = {}, q[CPL] = {};
  const int NW = gridDim.x * 4;
  for (int r = blockIdx.x * 4 + w; r < B; r += NW) {
    if (CPL == 2) {
      unsigned int u = *(const unsigned int*)(Z + (size_t)r * C + lane * 2);
      float v0 = b2f((unsigned short)u);
      float v1 = b2f((unsigned short)(u >> 16));
      s[0] += v0; q[0] += (double)v0 * (double)v0;
      s[1] += v1; q[1] += (double)v1 * (double)v1;
    } else {
      float v0 = b2f(Z[(size_t)r * C + lane]);
      s[0] += v0; q[0] += (double)v0 * (double)v0;
    }
  }
#pragma unroll
  for (int k = 0; k < CPL; ++k) { sS[w][lane * CPL + k] = s[k]; sQ[w][lane * CPL + k] = q[k]; }
  __syncthreads();
  if (t < C) {
    double ts = sS[0][t] + sS[1][t] + sS[2][t] + sS[3][t];
    double tq = sQ[0][t] + sQ[1][t] + sQ[2][t] + sQ[3][t];
    atomicAdd(&st[t], ts);
    atomicAdd(&st[C + t], tq);
  }
}

__global__ void k_bnfin(const double* __restrict__ st, int B, int C,
                        const float* __restrict__ g, const float* __restrict__ be,
                        float* __restrict__ ss) {
  int c = threadIdx.x;
  if (c < C) {
    double m = st[c] / B;
    double v = st[C + c] / B - m * m;
    if (v < 0) v = 0;
    float sc = (float)((double)g[c] / sqrt(v + 1e-5));
    ss[c] = sc;
    ss[C + c] = be[c] - (float)m * sc;
  }
}

__global__ void k_final(const unsigned short* __restrict__ Z3, const float* __restrict__ ss3,
                        const float* __restrict__ Wo, const float* __restrict__ bo,
                        void* __restrict__ out, int B, const int* __restrict__ flagp) {
  __shared__ float w[64], sc[64], sh[64];
  if (threadIdx.x < 64) {
    w[threadIdx.x] = Wo[threadIdx.x];
    sc[threadIdx.x] = ss3[threadIdx.x];
    sh[threadIdx.x] = ss3[64 + threadIdx.x];
  }
  __syncthreads();
  const int bf = *flagp;
  const float bb = bo[0];
  for (int r = blockIdx.x * blockDim.x + threadIdx.x; r < B; r += gridDim.x * blockDim.x) {
    const unsigned short* z = &Z3[(size_t)r * 64];
    float acc = bb;
#pragma unroll
    for (int k = 0; k < 64; ++k) {
      float y = fmaf(b2f(z[k]), sc[k], sh[k]);
      y = y > 0.f ? y : 0.f;
      acc = fmaf(y, w[k], acc);
    }
    float sv = 1.f / (1.f + expf(-acc));
    if (bf) ((unsigned short*)out)[r] = f2b(sv);
    else ((float*)out)[r] = sv;
  }
}

extern "C" void kernel_launch(void* const* d_in, const int* in_sizes, int n_in,
                              void* d_out, int out_size, void* d_ws, size_t ws_size,
                              hipStream_t stream) {
  enum { N_DR = 8000, N_P = 20000, N_DIS = 5000, N_MF = 3000, N_BP = 8000,
         N_CC = 2000, N_PATH = 2392 };
  if (n_in < 59) return;
  const int B = in_sizes[0];
  const int* x_dr = (const int*)d_in[0];
  const int* x_p  = (const int*)d_in[1];

  char* base = (char*)d_ws;
  size_t off = 0;
  auto alloc = [&](size_t bytes) -> void* {
    void* p = base + off;
    off += (bytes + 255) & ~(size_t)255;
    return p;
  };
  int*    flagp = (int*)alloc(256);
  double* st1 = (double*)alloc(896 * sizeof(double));
  double* st2 = st1 + 512; double* st3 = st2 + 256;
  float*  ss1 = (float*)alloc(896 * sizeof(float));
  float*  ss2 = ss1 + 512; float* ss3 = ss2 + 256;
  float*  pbuf = (float*)alloc(6000 * sizeof(float));
  unsigned short* wbf = (unsigned short*)alloc(1100000 * 2);
  unsigned short* DR  = (unsigned short*)alloc((size_t)N_DR * 384 * 2);
  unsigned short* P   = (unsigned short*)alloc((size_t)N_P * 512 * 2);
  unsigned short* h_d = (unsigned short*)alloc((size_t)N_DIS * 128 * 2);
  unsigned short* d1b = (unsigned short*)alloc((size_t)N_DIS * 128 * 2);
  unsigned short* z1  = (unsigned short*)alloc((size_t)B * 256 * 2);
  char* arena = (char*)alloc(44u * 1024 * 1024);
  if (off > ws_size) return;

  unsigned short* ar = (unsigned short*)arena;
  unsigned short* A_hmf  = ar;
  unsigned short* A_hbp  = A_hmf + (size_t)N_MF * 128;
  unsigned short* A_hcc  = A_hbp + (size_t)N_BP * 128;
  unsigned short* A_hpath= A_hcc + (size_t)N_CC * 128;
  unsigned short* A_gomf = A_hpath + (size_t)N_PATH * 128;
  unsigned short* A_gobp = A_gomf + (size_t)N_MF * 128;
  unsigned short* A_gocc = A_gobp + (size_t)N_BP * 128;
  unsigned short* ag17 = A_gocc + (size_t)N_CC * 128;
  unsigned short* ag18 = ag17 + (size_t)N_MF * 128;
  unsigned short* ag19 = ag18 + (size_t)N_BP * 128;
  unsigned short* ag20 = ag19 + (size_t)N_CC * 128;
  unsigned short* ag21 = ag20 + (size_t)N_P * 128;
  unsigned short* ag22 = ag21 + (size_t)N_P * 128;
  unsigned short* ag23 = ag22 + (size_t)N_P * 128;
  unsigned short* pl0 = ar;
  unsigned short* pl1 = pl0 + (size_t)N_DIS * 128;
  unsigned short* pl2 = pl1 + (size_t)N_DIS * 128;
  unsigned short* pl3 = pl2 + (size_t)N_DIS * 128;
  unsigned short* pl4 = pl3 + (size_t)N_DR * 128;
  unsigned short* pl5 = pl4 + (size_t)N_DR * 128;
  unsigned short* pl6 = pl5 + (size_t)N_P * 128;
  unsigned short* pl7 = pl6 + (size_t)N_DR * 128;
  unsigned short* ag9  = pl7 + (size_t)N_P * 128;
  unsigned short* ag10 = ag9 + (size_t)N_DR * 128;
  unsigned short* ag11 = ag10 + (size_t)N_DR * 128;
  unsigned short* ag12 = ag11 + (size_t)N_P * 128;
  unsigned short* ag13 = ag12 + (size_t)N_DIS * 128;
  unsigned short* ag14 = ag13 + (size_t)N_DIS * 128;
  unsigned short* ag15 = ag14 + (size_t)N_DIS * 128;
  unsigned short* ag16 = ag15 + (size_t)N_DR * 128;
  unsigned short* U_dr = ar;
  unsigned short* U_p  = U_dr + (size_t)N_DR * 256;
  unsigned short* z2 = U_p + (size_t)N_P * 256;
  unsigned short* z3 = z1;
  int* slot_arena = (int*)arena;

  k_flag<<<1, 64, 0, stream>>>((const unsigned int*)d_in[5], flagp);

  float* pp[59] = {};
  {
    PArgs pa;
    const int pidx[NPT] = {25,27,29,31,33,35,37,39,41,44,46,47,48,50,51,52,54,55,56,57,58};
    size_t poff = 0;
    for (int l = 0; l < NPT; ++l) {
      int i = pidx[l];
      pa.t[l].src = d_in[i]; pa.t[l].dst = pbuf + poff; pa.t[l].n = in_sizes[i]; pa.t[l].pad = 0;
      pp[i] = pbuf + poff;
      poff += in_sizes[i];
    }
    k_cv_params<<<dim3(4, NPT), 256, 0, stream>>>(pa, flagp);
  }

  unsigned short *Wdr_t, *Wpe_t, *Wde_t, *Wg_t, *Wps_t, *Wss_t, *Wns_t, *W1_t, *W2_t, *W3_t;
  {
    WArgs wa;
    int l = 0; size_t woff = 0;
    auto add = [&](int inIdx, int eoff, int K, int N) -> unsigned short* {
      unsigned short* dst = wbf + woff;
      wa.t[l].src = d_in[inIdx]; wa.t[l].dst = dst; wa.t[l].K = K; wa.t[l].N = N;
      wa.t[l].eoff = eoff; wa.t[l].pad = 0;
      ++l; woff += (size_t)K * N;
      return dst;
    };
    Wdr_t = add(24, 0, 1024, 128);
    Wpe_t = add(26, 0, 400, 128);
    Wde_t = add(28, 0, 512, 128);
    Wg_t = wbf + woff;
    for (int j = 0; j < 7; ++j) add(38, j * 16384, 128, 128);
    Wps_t = wbf + woff;
    for (int j = 0; j < 8; ++j) add(40, j * 16384, 128, 128);
    Wss_t = wbf + woff;
    for (int j = 0; j < 8; ++j) add(42, j * 16384, 128, 128);
    Wns_t = wbf + woff;
    for (int j = 0; j < 8; ++j) add(43, j * 16384, 128, 128);
    W1_t = add(45, 0, 896, 256);
    W2_t = add(49, 0, 256, 128);
    W3_t = add(53, 0, 128, 64);
    k_cv_wt<<<dim3(32, NWT), 256, 0, stream>>>(wa, flagp);
  }

  const int list_ei[NCSR] = {9, 10, 11, 12, 13, 14, 15, 16, 17, 18, 19, 20, 21, 22, 23};
  const int list_nd[NCSR] = {N_DR, N_DR, N_P, N_DIS, N_DIS, N_DIS, N_DR, N_P,
                             N_MF, N_BP, N_CC, N_P, N_P, N_P, N_P};
  int* rp[24]; unsigned short* cs[24];
  CsrArgs csra;
  {
    int* ip = (int*)z1;
    int* rp0 = ip;
    for (int l = 0; l < NCSR; ++l) { csra.d[l].rowptr = ip; rp[list_ei[l]] = ip; ip += list_nd[l] + 1; }
    size_t rp_total = (size_t)(ip - rp0);
    unsigned short* up = (unsigned short*)ip;
    size_t slotoff = 0;
    for (int l = 0; l < NCSR; ++l) {
      int ei = list_ei[l];
      int E = in_sizes[ei] / 2;
      csra.d[l].src = (const int*)d_in[ei];
      csra.d[l].dst = (const int*)d_in[ei] + E;
      csra.d[l].E = E;
      csra.d[l].n_dst = list_nd[l];
      csra.d[l].csrc = up; cs[ei] = up;
      csra.d[l].slot = slot_arena + slotoff;
      csra.d[l].pad = 0;
      up += E;
      slotoff += E;
    }
    hipMemsetAsync(rp0, 0, rp_total * sizeof(int), stream);
  }
  k_csr_count<<<dim3(96, NCSR), 256, 0, stream>>>(csra);
  k_csr_scan<<<NCSR, 1024, 0, stream>>>(csra);
  k_csr_fill<<<dim3(96, NCSR), 256, 0, stream>>>(csra);

  hipMemsetAsync(st1, 0, 896 * sizeof(double), stream);

  {
    EArgs ea;
    ea.t[0] = {d_in[2], Wdr_t, pp[25], DR, N_DR, 1024, 384, 0};
    ea.t[1] = {d_in[3], Wpe_t, pp[27], P, N_P, 400, 512, 0};
    ea.t[2] = {d_in[4], Wde_t, pp[29], h_d, N_DIS, 512, 128, 0};
    k_embed_multi<<<dim3((N_P + 63) / 64, 3), 256, 0, stream>>>(ea, flagp);
  }
  {
    BArgs ba;
    ba.t[0] = {d_in[30], pp[31], A_hmf, N_MF * 128, {}};
    ba.t[1] = {d_in[32], pp[33], A_hbp, N_BP * 128, {}};
    ba.t[2] = {d_in[34], pp[35], A_hcc, N_CC * 128, {}};
    ba.t[3] = {d_in[36], pp[37], A_hpath, N_PATH * 128, {}};
    k_biasrelu_multi<<<dim3(256, 4), 256, 0, stream>>>(ba, flagp);
  }

  auto mkpass = [](MTask& T, int i, const unsigned short* A, int lda, const unsigned short* W,
                   int ldw, const float* bias, int end) {
    T.p[i].A = A; T.p[i].lda = lda; T.p[i].W = W; T.p[i].ldw = ldw;
    T.p[i].bias = bias; T.p[i].flags = end;
  };
  const float* bg = pp[39];
  const float* bp_s = pp[41];
  const float* b_s = pp[44];

  {
    GArgs ga;
    ga.t[0] = {rp[17], cs[17], A_hmf, ag17, N_MF, 128, 0, 0};
    ga.t[1] = {rp[18], cs[18], A_hbp, ag18, N_BP, 128, 0, 0};
    ga.t[2] = {rp[19], cs[19], A_hcc, ag19, N_CC, 128, 0, 0};
    k_gather_multi<<<dim3((N_BP + 3) / 4, 3), 256, 0, stream>>>(ga);
  }
  {
    MArgs ma;
    for (int i = 0; i < 3; ++i) {
      MTask& T = ma.t[i];
      const unsigned short* aggp = (i == 0) ? ag17 : (i == 1) ? ag18 : ag19;
      const unsigned short* Rp = (i == 0) ? A_hmf : (i == 1) ? A_hbp : A_hcc;
      unsigned short* Cp = (i == 0) ? A_gomf : (i == 1) ? A_gobp : A_gocc;
      int n = (i == 0) ? N_MF : (i == 1) ? N_BP : N_CC;
      mkpass(T, 0, aggp, 128, Wg_t + (size_t)i * 16384, 128, bg + i * 128, 1);
      T.npass = 1; T.n = n; T.K = 128; T.R = Rp; T.C = Cp; T.ldc = 128; T.relu = 1;
    }
    k_mg<<<dim3((N_BP + 63) / 64, 3), 256, 0, stream>>>(ma);
  }
  {
    GArgs ga;
    ga.t[0] = {rp[20], cs[20], A_gomf, ag20, N_P, 128, 0, 0};
    ga.t[1] = {rp[21], cs[21], A_gobp, ag21, N_P, 128, 0, 0};
    ga.t[2] = {rp[22], cs[22], A_gocc, ag22, N_P, 128, 0, 0};
    ga.t[3] = {rp[23], cs[23], A_hpath, ag23, N_P, 128, 0, 0};
    k_gather_multi<<<dim3((N_P + 3) / 4, 4), 256, 0, stream>>>(ga);
  }
  {
    MArgs ma;
    MTask& T = ma.t[0];
    mkpass(T, 0, ag20, 128, Wg_t + 3 * 16384, 128, bg + 3 * 128, 1);
    mkpass(T, 1, ag21, 128, Wg_t + 4 * 16384, 128, bg + 4 * 128, 1);
    mkpass(T, 2, ag22, 128, Wg_t + 5 * 16384, 128, bg + 5 * 128, 1);
    mkpass(T, 3, ag23, 128, Wg_t + 6 * 16384, 128, bg + 6 * 128, 1);
    T.npass = 4; T.n = N_P; T.K = 128; T.R = nullptr; T.C = P + 384; T.ldc = 512; T.relu = 1;
    k_mg<<<dim3((N_P + 63) / 64, 1), 256, 0, stream>>>(ma);
  }

  {
    MArgs ma;
    const unsigned short* xs[8] = {h_d, h_d, h_d, DR, DR, P, DR, P};
    const int lda[8] = {128, 128, 128, 384, 384, 512, 384, 512};
    const int nn[8] = {N_DIS, N_DIS, N_DIS, N_DR, N_DR, N_P, N_DR, N_P};
    unsigned short* plo[8] = {pl0, pl1, pl2, pl3, pl4, pl5, pl6, pl7};
    for (int i = 0; i < 8; ++i) {
      MTask& T = ma.t[i];
      mkpass(T, 0, xs[i], lda[i], Wps_t + (size_t)i * 16384, 128, bp_s + i * 128, 1);
      T.npass = 1; T.n = nn[i]; T.K = 128; T.R = nullptr; T.C = plo[i]; T.ldc = 128; T.relu = 1;
    }
    k_mg<<<dim3((N_P + 63) / 64, 8), 256, 0, stream>>>(ma);
  }
  {
    GArgs ga;
    ga.t[0] = {rp[9],  cs[9],  pl0, ag9,  N_DR, 128, 1, 0};
    ga.t[1] = {rp[10], cs[10], pl1, ag10, N_DR, 128, 1, 0};
    ga.t[2] = {rp[11], cs[11], pl2, ag11, N_P, 128, 1, 0};
    ga.t[3] = {rp[12], cs[12], pl3, ag12, N_DIS, 128, 1, 0};
    ga.t[4] = {rp[13], cs[13], pl4, ag13, N_DIS, 128, 1, 0};
    ga.t[5] = {rp[14], cs[14], pl5, ag14, N_DIS, 128, 1, 0};
    ga.t[6] = {rp[15], cs[15], pl6, ag15, N_DR, 128, 1, 0};
    ga.t[7] = {rp[16], cs[16], pl7, ag16, N_P, 128, 1, 0};
    k_gather_multi<<<dim3((N_P + 3) / 4, 8), 256, 0, stream>>>(ga);
  }
  {
    MArgs ma;
    {
      MTask& T = ma.t[0];
      mkpass(T, 0, DR, 384, Wss_t + (size_t)0 * 16384, 128, nullptr, 0);
      mkpass(T, 1, ag9, 128, Wns_t + (size_t)0 * 16384, 128, b_s + 0 * 128, 1);
      mkpass(T, 2, DR, 384, Wss_t + (size_t)1 * 16384, 128, nullptr, 0);
      mkpass(T, 3, ag10, 128, Wns_t + (size_t)1 * 16384, 128, b_s + 1 * 128, 1);
      mkpass(T, 4, DR, 384, Wss_t + (size_t)6 * 16384, 128, nullptr, 0);
      mkpass(T, 5, ag15, 128, Wns_t + (size_t)6 * 16384, 128, b_s + 6 * 128, 1);
      T.npass = 6; T.n = N_DR; T.K = 128; T.R = nullptr; T.C = DR + 128; T.ldc = 384; T.relu = 1;
    }
    {
      MTask& T = ma.t[1];
      mkpass(T, 0, P, 512, Wss_t + (size_t)2 * 16384, 128, nullptr, 0);
      mkpass(T, 1, ag11, 128, Wns_t + (size_t)2 * 16384, 128, b_s + 2 * 128, 1);
      mkpass(T, 2, P, 512, Wss_t + (size_t)7 * 16384, 128, nullptr, 0);
      mkpass(T, 3, ag16, 128, Wns_t + (size_t)7 * 16384, 128, b_s + 7 * 128, 1);
      T.npass = 4; T.n = N_P; T.K = 128; T.R = nullptr; T.C = P + 128; T.ldc = 512; T.relu = 1;
    }
    {
      MTask& T = ma.t[2];
      mkpass(T, 0, h_d, 128, Wss_t + (size_t)3 * 16384, 128, nullptr, 0);
      mkpass(T, 1, ag12, 128, Wns_t + (size_t)3 * 16384, 128, b_s + 3 * 128, 1);
      mkpass(T, 2, h_d, 128, Wss_t + (size_t)4 * 16384, 128, nullptr, 0);
      mkpass(T, 3, ag13, 128, Wns_t + (size_t)4 * 16384, 128, b_s + 4 * 128, 1);
      mkpass(T, 4, h_d, 128, Wss_t + (size_t)5 * 16384, 128, nullptr, 0);
      mkpass(T, 5, ag14, 128, Wns_t + (size_t)5 * 16384, 128, b_s + 5 * 128, 1);
      T.npass = 6; T.n = N_DIS; T.K = 128; T.R = nullptr; T.C = d1b; T.ldc = 128; T.relu = 1;
    }
    k_mg<<<dim3((N_P + 63) / 64, 3), 256, 0, stream>>>(ma);
  }

  {
    MArgs ma;
    const unsigned short* xs[5] = {d1b, d1b, d1b, DR + 128, P + 128};
    const int lda[5] = {128, 128, 128, 384, 512};
    const int nn[5] = {N_DIS, N_DIS, N_DIS, N_DR, N_P};
    unsigned short* plo[5] = {pl0, pl1, pl2, pl6, pl7};
    const int si[5] = {0, 1, 2, 6, 7};
    for (int i = 0; i < 5; ++i) {
      MTask& T = ma.t[i];
      mkpass(T, 0, xs[i], lda[i], Wps_t + (size_t)si[i] * 16384, 128, bp_s + si[i] * 128, 1);
      T.npass = 1; T.n = nn[i]; T.K = 128; T.R = nullptr; T.C = plo[i]; T.ldc = 128; T.relu = 1;
    }
    k_mg<<<dim3((N_P + 63) / 64, 5), 256, 0, stream>>>(ma);
  }
  {
    GArgs ga;
    ga.t[0] = {rp[9],  cs[9],  pl0, ag9,  N_DR, 128, 1, 0};
    ga.t[1] = {rp[10], cs[10], pl1, ag10, N_DR, 128, 1, 0};
    ga.t[2] = {rp[11], cs[11], pl2, ag11, N_P, 128, 1, 0};
    ga.t[3] = {rp[15], cs[15], pl6, ag15, N_DR, 128, 1, 0};
    ga.t[4] = {rp[16], cs[16], pl7, ag16, N_P, 128, 1, 0};
    k_gather_multi<<<dim3((N_P + 3) / 4, 5), 256, 0, stream>>>(ga);
  }
  {
    MArgs ma;
    {
      MTask& T = ma.t[0];
      mkpass(T, 0, DR + 128, 384, Wss_t + (size_t)0 * 16384, 128, nullptr, 0);
      mkpass(T, 1, ag9, 128, Wns_t + (size_t)0 * 16384, 128, b_s + 0 * 128, 1);
      mkpass(T, 2, DR + 128, 384, Wss_t + (size_t)1 * 16384, 128, nullptr, 0);
      mkpass(T, 3, ag10, 128, Wns_t + (size_t)1 * 16384, 128, b_s + 1 * 128, 1);
      mkpass(T, 4, DR + 128, 384, Wss_t + (size_t)6 * 16384, 128, nullptr, 0);
      mkpass(T, 5, ag15, 128, Wns_t + (size_t)6 * 16384, 128, b_s + 6 * 128, 1);
      T.npass = 6; T.n = N_DR; T.K = 128; T.R = nullptr; T.C = DR + 256; T.ldc = 384; T.relu = 1;
    }
    {
      MTask& T = ma.t[1];
      mkpass(T, 0, P + 128, 512, Wss_t + (size_t)2 * 16384, 128, nullptr, 0);
      mkpass(T, 1, ag11, 128, Wns_t + (size_t)2 * 16384, 128, b_s + 2 * 128, 1);
      mkpass(T, 2, P + 128, 512, Wss_t + (size_t)7 * 16384, 128, nullptr, 0);
      mkpass(T, 3, ag16, 128, Wns_t + (size_t)7 * 16384, 128, b_s + 7 * 128, 1);
      T.npass = 4; T.n = N_P; T.K = 128; T.R = nullptr; T.C = P + 256; T.ldc = 512; T.relu = 1;
    }
    k_mg<<<dim3((N_P + 63) / 64, 2), 256, 0, stream>>>(ma);
  }

  {
    MArgs ma;
    for (int half = 0; half < 2; ++half) {
      {
        MTask& T = ma.t[half];
        mkpass(T, 0, DR, 384, W1_t + (size_t)(half * 128) * 896, 896, pp[46] + half * 128, 1);
        T.npass = 1; T.n = N_DR; T.K = 384; T.R = nullptr;
        T.C = U_dr + half * 128; T.ldc = 256; T.relu = 0;
      }
      {
        MTask& T = ma.t[2 + half];
        mkpass(T, 0, P, 512, W1_t + (size_t)(half * 128) * 896 + 384, 896, nullptr, 1);
        T.npass = 1; T.n = N_P; T.K = 512; T.R = nullptr;
        T.C = U_p + half * 128; T.ldc = 256; T.relu = 0;
      }
    }
    k_mg<<<dim3((N_P + 63) / 64, 4), 256, 0, stream>>>(ma);
  }

  k_hstat<<<256, 256, 0, stream>>>(x_dr, x_p, U_dr, U_p, st1, B);
  k_bnfin<<<1, 256, 0, stream>>>(st1, B, 256, pp[47], pp[48], ss1);

  k_gemm_bn1<<<(B + 63) / 64, 256, 0, stream>>>(x_dr, x_p, U_dr, U_p, W2_t, pp[50], ss1, z2, B);
  k_bnst<128><<<256, 256, 0, stream>>>(z2, B, st2);
  k_bnfin<<<1, 128, 0, stream>>>(st2, B, 128, pp[51], pp[52], ss2);

  k_gemm_bn<64><<<(B + 63) / 64, 256, 0, stream>>>(z2, W3_t, pp[54], ss2, z3, B, 128);
  k_bnst<64><<<256, 256, 0, stream>>>(z3, B, st3);
  k_bnfin<<<1, 64, 0, stream>>>(st3, B, 64, pp[55], pp[56], ss3);

  k_final<<<256, 256, 0, stream>>>(z3, ss3, pp[57], pp[58], d_out, B, flagp);
}

// Round 8
// 1205.726 us; speedup vs baseline: 1.1024x; 1.1024x over previous
//
#include <hip/hip_runtime.h>

#define NCSR 15
#define MAXP 6
#define MAXT 8
#define NPT 21
#define NWT 37

typedef __attribute__((ext_vector_type(8))) short bfrag;
typedef __attribute__((ext_vector_type(4))) float ffrag;

__device__ __forceinline__ float b2f(unsigned short s) {
  return __uint_as_float(((unsigned int)s) << 16);
}
__device__ __forceinline__ unsigned short f2b(float f) {
  unsigned int u = __float_as_uint(f);
  u = (u + 0x7FFFu + ((u >> 16) & 1u)) >> 16;
  return (unsigned short)u;
}
__device__ __forceinline__ float ldf(const void* p, size_t i, int bf) {
  if (bf) return b2f(((const unsigned short*)p)[i]);
  return ((const float*)p)[i];
}
// load 8 consecutive raw elements (flag dtype) -> packed 8x bf16 in int4
__device__ __forceinline__ int4 ld8(const void* p, size_t i, int bf) {
  if (bf) return *(const int4*)((const unsigned short*)p + i);
  const float* pf = (const float*)p + i;
  float4 f0 = *(const float4*)pf;
  float4 f1 = *(const float4*)(pf + 4);
  int4 v;
  v.x = (int)((unsigned)f2b(f0.x) | ((unsigned)f2b(f0.y) << 16));
  v.y = (int)((unsigned)f2b(f0.z) | ((unsigned)f2b(f0.w) << 16));
  v.z = (int)((unsigned)f2b(f1.x) | ((unsigned)f2b(f1.y) << 16));
  v.w = (int)((unsigned)f2b(f1.z) | ((unsigned)f2b(f1.w) << 16));
  return v;
}

struct CsrDesc {
  const int* src; const int* dst; int E; int n_dst;
  int* rowptr; unsigned short* csrc; int* slot; int pad;
};
struct CsrArgs { CsrDesc d[NCSR]; };

struct PTask { const void* src; float* dst; int n; int pad; };
struct PArgs { PTask t[NPT]; };

struct WTask { const void* src; unsigned short* dst; int K; int N; int eoff; int pad; };
struct WArgs { WTask t[NWT]; };

struct MPass { const unsigned short* A; const unsigned short* W; const float* bias; int lda; int ldw; int flags; };
struct MTask {
  MPass p[MAXP];
  const unsigned short* R; unsigned short* C;
  int npass, n, K, ldc, relu, pad;
};
struct MArgs { MTask t[MAXT]; };

struct GTask { const int* rowptr; const unsigned short* csrc; const unsigned short* X; unsigned short* out; int n_dst; int ldx; int mode; int pad; };
struct GArgs { GTask t[MAXT]; };

struct ETask { const void* A; const unsigned short* W; const float* bias; unsigned short* C; int n, K, ldc, pad; };
struct EArgs { ETask t[3]; };

struct BTask { const void* w; const float* b; unsigned short* out; int n; int pad[3]; };
struct BArgs { BTask t[4]; };

__global__ void k_flag(const unsigned int* probe, int* flag) {
  if (threadIdx.x == 0) *flag = (probe[0] == 0x3F800000u) ? 0 : 1;
}

__global__ void k_cv_params(PArgs args, const int* __restrict__ flagp) {
  const int bf = *flagp;
  const PTask T = args.t[blockIdx.y];
  for (int i = blockIdx.x * blockDim.x + threadIdx.x; i < T.n; i += gridDim.x * blockDim.x)
    T.dst[i] = ldf(T.src, (size_t)i, bf);
}

__global__ void k_cv_wt(WArgs args, const int* __restrict__ flagp) {
  const int bf = *flagp;
  const WTask T = args.t[blockIdx.y];
  const int total = T.K * T.N;
  const size_t eoff = (size_t)T.eoff;
  for (int i = blockIdx.x * blockDim.x + threadIdx.x; i < total; i += gridDim.x * blockDim.x) {
    int n = i / T.K, k = i - n * T.K;
    T.dst[i] = f2b(ldf(T.src, eoff + (size_t)k * T.N + n, bf));
  }
}

// identity-feature embeddings, vectorized 8 elems/thread: out = bf16(relu(w + b[c]))
__global__ void k_biasrelu_multi(BArgs args, const int* __restrict__ flagp) {
  const int bf = *flagp;
  const BTask T = args.t[blockIdx.y];
  const int n8 = T.n >> 3;
  for (int i = blockIdx.x * blockDim.x + threadIdx.x; i < n8; i += gridDim.x * blockDim.x) {
    int base = i << 3;
    int4 v = ld8(T.w, (size_t)base, bf);
    const unsigned short* pv = (const unsigned short*)&v;
    const int cb = base & 127;
    unsigned short o[8];
#pragma unroll
    for (int j = 0; j < 8; ++j) {
      float f = b2f(pv[j]) + T.b[cb + j];
      o[j] = f2b(f > 0.f ? f : 0.f);
    }
    *(int4*)(T.out + base) = *(const int4*)o;
  }
}

// count pass: returned old value IS the edge's slot within its dst row
__global__ void k_csr_count(CsrArgs args) {
  const CsrDesc cd = args.d[blockIdx.y];
  for (int e = blockIdx.x * blockDim.x + threadIdx.x; e < cd.E; e += gridDim.x * blockDim.x)
    cd.slot[e] = atomicAdd(&cd.rowptr[cd.dst[e] + 1], 1);
}

__global__ void k_csr_scan(CsrArgs args) {
  const CsrDesc cd = args.d[blockIdx.x];
  const int n = cd.n_dst + 1;
  const int t = threadIdx.x;
  const int lane = t & 63, w = t >> 6;
  __shared__ int wsum[16];
  int carry = 0;
  for (int base = 0; base < n; base += 1024) {
    int i = base + t;
    int v = (i < n) ? cd.rowptr[i] : 0;
    for (int off = 1; off < 64; off <<= 1) {
      int u = __shfl_up(v, off, 64);
      if (lane >= off) v += u;
    }
    if (lane == 63) wsum[w] = v;
    __syncthreads();
    if (w == 0) {
      int s = (lane < 16) ? wsum[lane] : 0;
      for (int off = 1; off < 16; off <<= 1) {
        int u = __shfl_up(s, off, 64);
        if (lane >= off) s += u;
      }
      if (lane < 16) wsum[lane] = s;
    }
    __syncthreads();
    int nv = v + carry + (w > 0 ? wsum[w - 1] : 0);
    if (i < n) cd.rowptr[i] = nv;
    carry += wsum[15];
    __syncthreads();
  }
}

// fill: deterministic placement, no atomics; csrc ushort (all src counts < 65536)
__global__ void k_csr_fill(CsrArgs args) {
  const CsrDesc cd = args.d[blockIdx.y];
  for (int e = blockIdx.x * blockDim.x + threadIdx.x; e < cd.E; e += gridDim.x * blockDim.x) {
    int d = cd.dst[e];
    cd.csrc[cd.rowptr[d] + cd.slot[e]] = (unsigned short)cd.src[e];
  }
}

// one wave per dst row; lane = one uint = 2 bf16 cols; 4-edge unroll
__global__ void k_gather_multi(GArgs args) {
  const GTask T = args.t[blockIdx.y];
  int w = (blockIdx.x * blockDim.x + threadIdx.x) >> 6;
  if (w >= T.n_dst) return;
  int lane = threadIdx.x & 63;
  int beg = T.rowptr[w], end = T.rowptr[w + 1];
  float a0 = 0.f, a1 = 0.f;
  int j = beg;
  if (T.mode == 0) {
    for (; j + 3 < end; j += 4) {
      unsigned int u0 = ((const unsigned int*)(T.X + (size_t)T.csrc[j] * T.ldx))[lane];
      unsigned int u1 = ((const unsigned int*)(T.X + (size_t)T.csrc[j + 1] * T.ldx))[lane];
      unsigned int u2 = ((const unsigned int*)(T.X + (size_t)T.csrc[j + 2] * T.ldx))[lane];
      unsigned int u3 = ((const unsigned int*)(T.X + (size_t)T.csrc[j + 3] * T.ldx))[lane];
      a0 += __uint_as_float(u0 << 16) + __uint_as_float(u1 << 16)
          + __uint_as_float(u2 << 16) + __uint_as_float(u3 << 16);
      a1 += __uint_as_float(u0 & 0xFFFF0000u) + __uint_as_float(u1 & 0xFFFF0000u)
          + __uint_as_float(u2 & 0xFFFF0000u) + __uint_as_float(u3 & 0xFFFF0000u);
    }
    for (; j < end; ++j) {
      unsigned int u0 = ((const unsigned int*)(T.X + (size_t)T.csrc[j] * T.ldx))[lane];
      a0 += __uint_as_float(u0 << 16);
      a1 += __uint_as_float(u0 & 0xFFFF0000u);
    }
  } else {
    for (; j + 3 < end; j += 4) {
      unsigned int u0 = ((const unsigned int*)(T.X + (size_t)T.csrc[j] * T.ldx))[lane];
      unsigned int u1 = ((const unsigned int*)(T.X + (size_t)T.csrc[j + 1] * T.ldx))[lane];
      unsigned int u2 = ((const unsigned int*)(T.X + (size_t)T.csrc[j + 2] * T.ldx))[lane];
      unsigned int u3 = ((const unsigned int*)(T.X + (size_t)T.csrc[j + 3] * T.ldx))[lane];
      a0 = fmaxf(fmaxf(a0, fmaxf(__uint_as_float(u0 << 16), __uint_as_float(u1 << 16))),
                 fmaxf(__uint_as_float(u2 << 16), __uint_as_float(u3 << 16)));
      a1 = fmaxf(fmaxf(a1, fmaxf(__uint_as_float(u0 & 0xFFFF0000u), __uint_as_float(u1 & 0xFFFF0000u))),
                 fmaxf(__uint_as_float(u2 & 0xFFFF0000u), __uint_as_float(u3 & 0xFFFF0000u)));
    }
    for (; j < end; ++j) {
      unsigned int u0 = ((const unsigned int*)(T.X + (size_t)T.csrc[j] * T.ldx))[lane];
      a0 = fmaxf(a0, __uint_as_float(u0 << 16));
      a1 = fmaxf(a1, __uint_as_float(u0 & 0xFFFF0000u));
    }
  }
  unsigned int* po = (unsigned int*)(T.out + (size_t)w * 128);
  po[lane] = (unsigned int)f2b(a0) | ((unsigned int)f2b(a1) << 16);
}

// MFMA multi-task group GEMM, 64-row x 128-col tile per 256-thread block
__launch_bounds__(256)
__global__ void k_mg(MArgs args) {
  const MTask* T = &args.t[blockIdx.y];
  const int n = T->n;
  const int row0 = blockIdx.x * 64;
  if (row0 >= n) return;
  __shared__ __align__(16) unsigned short As[64][40];
  __shared__ __align__(16) unsigned short Ws[128][40];
  const int t = threadIdx.x;
  const int wave = t >> 6, lane = t & 63;
  const int m16 = lane & 15, kq = lane >> 4;
  const int K = T->K;
  ffrag acc[4][2], accO[4][2];
#pragma unroll
  for (int i = 0; i < 4; ++i)
#pragma unroll
    for (int j = 0; j < 2; ++j) { acc[i][j] = (ffrag)0.f; accO[i][j] = (ffrag)0.f; }
  const int colbase = wave * 32;
  for (int ip = 0; ip < T->npass; ++ip) {
    const unsigned short* Ap = T->p[ip].A;
    const unsigned short* Wp = T->p[ip].W;
    const int lda = T->p[ip].lda, ldw = T->p[ip].ldw;
    for (int k0 = 0; k0 < K; k0 += 32) {
      __syncthreads();
      {
        int r = t >> 2, c = t & 3;
        int row = row0 + r;
        int4 v = {0, 0, 0, 0};
        if (row < n) v = *(const int4*)(Ap + (size_t)row * lda + k0 + c * 8);
        *(int4*)&As[r][c * 8] = v;
      }
#pragma unroll
      for (int e = t; e < 512; e += 256) {
        int nn = e >> 2, c = e & 3;
        *(int4*)&Ws[nn][c * 8] = *(const int4*)(Wp + (size_t)nn * ldw + k0 + c * 8);
      }
      __syncthreads();
      bfrag b0 = *(const bfrag*)&Ws[colbase + m16][kq * 8];
      bfrag b1 = *(const bfrag*)&Ws[colbase + 16 + m16][kq * 8];
#pragma unroll
      for (int rb = 0; rb < 4; ++rb) {
        bfrag a = *(const bfrag*)&As[rb * 16 + m16][kq * 8];
        acc[rb][0] = __builtin_amdgcn_mfma_f32_16x16x32_bf16(a, b0, acc[rb][0], 0, 0, 0);
        acc[rb][1] = __builtin_amdgcn_mfma_f32_16x16x32_bf16(a, b1, acc[rb][1], 0, 0, 0);
      }
    }
    if (T->p[ip].flags & 1) {
      const float* bias = T->p[ip].bias;
      float bv0 = bias ? bias[colbase + m16] : 0.f;
      float bv1 = bias ? bias[colbase + 16 + m16] : 0.f;
#pragma unroll
      for (int rb = 0; rb < 4; ++rb)
#pragma unroll
        for (int cb = 0; cb < 2; ++cb) {
          float bv = cb ? bv1 : bv0;
#pragma unroll
          for (int r = 0; r < 4; ++r) {
            float v = acc[rb][cb][r] + bv;
            if (T->relu) v = v > 0.f ? v : 0.f;
            accO[rb][cb][r] += v;
          }
          acc[rb][cb] = (ffrag)0.f;
        }
    }
  }
  const int ldc = T->ldc;
#pragma unroll
  for (int rb = 0; rb < 4; ++rb)
#pragma unroll
    for (int cb = 0; cb < 2; ++cb) {
      int col = colbase + cb * 16 + m16;
#pragma unroll
      for (int r = 0; r < 4; ++r) {
        int row = row0 + rb * 16 + kq * 4 + r;
        if (row < n) {
          float v = accO[rb][cb][r];
          if (T->R) v += b2f(T->R[(size_t)row * ldc + col]);
          T->C[(size_t)row * ldc + col] = f2b(v);
        }
      }
    }
}

// MFMA embed from raw flag-dtype A, 32-row tile, VECTORIZED A staging
__launch_bounds__(256)
__global__ void k_embed_multi(EArgs args, const int* __restrict__ flagp) {
  const ETask T = args.t[blockIdx.y];
  const int n = T.n;
  const int row0 = blockIdx.x * 32;
  if (row0 >= n) return;
  const int bf = *flagp;
  __shared__ __align__(16) unsigned short As[32][40];
  __shared__ __align__(16) unsigned short Ws[128][40];
  const int t = threadIdx.x;
  const int wave = t >> 6, lane = t & 63;
  const int m16 = lane & 15, kq = lane >> 4;
  const int K = T.K;
  ffrag acc[2][2];
#pragma unroll
  for (int i = 0; i < 2; ++i)
#pragma unroll
    for (int j = 0; j < 2; ++j) acc[i][j] = (ffrag)0.f;
  const int colbase = wave * 32;
  for (int k0 = 0; k0 < K; k0 += 32) {
    __syncthreads();
    if (t < 128) {  // 32 rows x 4 chunks of 8
      int r = t >> 2, c = t & 3;
      int row = row0 + r, k = k0 + c * 8;
      int4 v = {0, 0, 0, 0};
      if (row < n && k < K) v = ld8(T.A, (size_t)row * K + k, bf);
      *(int4*)&As[r][c * 8] = v;
    }
#pragma unroll
    for (int e = t; e < 512; e += 256) {
      int nn = e >> 2, c = e & 3;
      int4 v = {0, 0, 0, 0};
      if (k0 + c * 8 < K) v = *(const int4*)(T.W + (size_t)nn * K + k0 + c * 8);
      *(int4*)&Ws[nn][c * 8] = v;
    }
    __syncthreads();
    bfrag a0 = *(const bfrag*)&As[m16][kq * 8];
    bfrag a1 = *(const bfrag*)&As[16 + m16][kq * 8];
    bfrag b0 = *(const bfrag*)&Ws[colbase + m16][kq * 8];
    bfrag b1 = *(const bfrag*)&Ws[colbase + 16 + m16][kq * 8];
    acc[0][0] = __builtin_amdgcn_mfma_f32_16x16x32_bf16(a0, b0, acc[0][0], 0, 0, 0);
    acc[0][1] = __builtin_amdgcn_mfma_f32_16x16x32_bf16(a0, b1, acc[0][1], 0, 0, 0);
    acc[1][0] = __builtin_amdgcn_mfma_f32_16x16x32_bf16(a1, b0, acc[1][0], 0, 0, 0);
    acc[1][1] = __builtin_amdgcn_mfma_f32_16x16x32_bf16(a1, b1, acc[1][1], 0, 0, 0);
  }
#pragma unroll
  for (int rb = 0; rb < 2; ++rb)
#pragma unroll
    for (int cb = 0; cb < 2; ++cb) {
      int col = colbase + cb * 16 + m16;
      float bv = T.bias[col];
#pragma unroll
      for (int r = 0; r < 4; ++r) {
        int row = row0 + rb * 16 + kq * 4 + r;
        if (row < n) {
          float v = acc[rb][cb][r] + bv;
          T.C[(size_t)row * T.ldc + col] = f2b(v > 0.f ? v : 0.f);
        }
      }
    }
}

// MFMA GEMM with BN+relu applied to bf16 A while staging; 64-row tile; vectorized A
template<int NC>
__launch_bounds__(256)
__global__ void k_gemm_bn(const unsigned short* __restrict__ A, const unsigned short* __restrict__ W,
                          const float* __restrict__ bias, const float* __restrict__ ss,
                          unsigned short* __restrict__ C, int n, int K) {
  constexpr int CB = NC / 64;
  __shared__ __align__(16) unsigned short As[64][40];
  __shared__ __align__(16) unsigned short Ws[NC][40];
  const int t = threadIdx.x;
  const int wave = t >> 6, lane = t & 63;
  const int m16 = lane & 15, kq = lane >> 4;
  const int row0 = blockIdx.x * 64;
  if (row0 >= n) return;
  ffrag acc[4][CB];
#pragma unroll
  for (int i = 0; i < 4; ++i)
#pragma unroll
    for (int j = 0; j < CB; ++j) acc[i][j] = (ffrag)0.f;
  const int colbase = wave * 16 * CB;
  for (int k0 = 0; k0 < K; k0 += 32) {
    __syncthreads();
    {  // 64 rows x 4 chunks of 8 = 256 threads
      int r = t >> 2, c = t & 3;
      int row = row0 + r, k = k0 + c * 8;
      int4 v = {0, 0, 0, 0};
      if (row < n) {
        int4 a8 = *(const int4*)(A + (size_t)row * K + k);
        const unsigned short* pa = (const unsigned short*)&a8;
        unsigned short o[8];
#pragma unroll
        for (int j = 0; j < 8; ++j) {
          float val = fmaf(b2f(pa[j]), ss[k + j], ss[K + k + j]);
          o[j] = f2b(val > 0.f ? val : 0.f);
        }
        v = *(const int4*)o;
      }
      *(int4*)&As[r][c * 8] = v;
    }
#pragma unroll
    for (int e = t; e < NC * 4; e += 256) {
      int nn = e >> 2, c = e & 3;
      *(int4*)&Ws[nn][c * 8] = *(const int4*)(W + (size_t)nn * K + k0 + c * 8);
    }
    __syncthreads();
#pragma unroll
    for (int cb = 0; cb < CB; ++cb) {
      bfrag b = *(const bfrag*)&Ws[colbase + cb * 16 + m16][kq * 8];
#pragma unroll
      for (int rb = 0; rb < 4; ++rb) {
        bfrag a = *(const bfrag*)&As[rb * 16 + m16][kq * 8];
        acc[rb][cb] = __builtin_amdgcn_mfma_f32_16x16x32_bf16(a, b, acc[rb][cb], 0, 0, 0);
      }
    }
  }
#pragma unroll
  for (int rb = 0; rb < 4; ++rb)
#pragma unroll
    for (int cb = 0; cb < CB; ++cb) {
      int col = colbase + cb * 16 + m16;
      float bv = bias[col];
#pragma unroll
      for (int r = 0; r < 4; ++r) {
        int row = row0 + rb * 16 + kq * 4 + r;
        if (row < n) C[(size_t)row * NC + col] = f2b(acc[rb][cb][r] + bv);
      }
    }
}

// BN1 stats over implicit z1[b] = Udr[x_dr[b]] + Up[x_p[b]] (never materialized)
__global__ void k_hstat(const int* __restrict__ xdr, const int* __restrict__ xp,
                        const unsigned short* __restrict__ Udr, const unsigned short* __restrict__ Up,
                        double* __restrict__ st, int B) {
  __shared__ double sS[4][256];
  __shared__ double sQ[4][256];
  const int t = threadIdx.x;
  const int lane = t & 63, w = t >> 6;
  const int c4 = lane * 4;
  double s0 = 0, s1 = 0, s2 = 0, s3 = 0, q0 = 0, q1 = 0, q2 = 0, q3 = 0;
  const int NW = gridDim.x * 4;
  for (int r = blockIdx.x * 4 + w; r < B; r += NW) {
    int i = xdr[r], j = xp[r];
    uint2 a = *(const uint2*)(Udr + (size_t)i * 256 + c4);
    uint2 b = *(const uint2*)(Up + (size_t)j * 256 + c4);
    float v0 = b2f((unsigned short)a.x) + b2f((unsigned short)b.x);
    float v1 = b2f((unsigned short)(a.x >> 16)) + b2f((unsigned short)(b.x >> 16));
    float v2 = b2f((unsigned short)a.y) + b2f((unsigned short)b.y);
    float v3 = b2f((unsigned short)(a.y >> 16)) + b2f((unsigned short)(b.y >> 16));
    s0 += v0; s1 += v1; s2 += v2; s3 += v3;
    q0 += (double)v0 * (double)v0; q1 += (double)v1 * (double)v1;
    q2 += (double)v2 * (double)v2; q3 += (double)v3 * (double)v3;
  }
  sS[w][c4] = s0; sS[w][c4 + 1] = s1; sS[w][c4 + 2] = s2; sS[w][c4 + 3] = s3;
  sQ[w][c4] = q0; sQ[w][c4 + 1] = q1; sQ[w][c4 + 2] = q2; sQ[w][c4 + 3] = q3;
  __syncthreads();
  double ts = sS[0][t] + sS[1][t] + sS[2][t] + sS[3][t];
  double tq = sQ[0][t] + sQ[1][t] + sQ[2][t] + sQ[3][t];
  atomicAdd(&st[t], ts);
  atomicAdd(&st[256 + t], tq);
}

// MLP layer 2: A gathered on the fly (z1 never materialized), BN1+relu inline; 64-row tile
__launch_bounds__(256)
__global__ void k_gemm_bn1(const int* __restrict__ xdr, const int* __restrict__ xp,
                           const unsigned short* __restrict__ Udr, const unsigned short* __restrict__ Up,
                           const unsigned short* __restrict__ W, const float* __restrict__ bias,
                           const float* __restrict__ ss, unsigned short* __restrict__ Co, int n) {
  __shared__ __align__(16) unsigned short As[64][40];
  __shared__ __align__(16) unsigned short Ws[128][40];
  __shared__ int gi[64], gj[64];
  const int t = threadIdx.x;
  const int wave = t >> 6, lane = t & 63;
  const int m16 = lane & 15, kq = lane >> 4;
  const int row0 = blockIdx.x * 64;
  if (row0 >= n) return;
  if (t < 64) {
    int row = row0 + t; if (row >= n) row = n - 1;
    gi[t] = xdr[row]; gj[t] = xp[row];
  }
  ffrag acc[4][2];
#pragma unroll
  for (int i = 0; i < 4; ++i)
#pragma unroll
    for (int j = 0; j < 2; ++j) acc[i][j] = (ffrag)0.f;
  const int colbase = wave * 32;
  __syncthreads();
  for (int k0 = 0; k0 < 256; k0 += 32) {
    __syncthreads();
#pragma unroll
    for (int e = t; e < 512; e += 256) {
      int r = e >> 3, seg = e & 7;
      int k = k0 + seg * 4;
      uint2 a = *(const uint2*)(Udr + (size_t)gi[r] * 256 + k);
      uint2 b = *(const uint2*)(Up + (size_t)gj[r] * 256 + k);
      float v0 = b2f((unsigned short)a.x) + b2f((unsigned short)b.x);
      float v1 = b2f((unsigned short)(a.x >> 16)) + b2f((unsigned short)(b.x >> 16));
      float v2 = b2f((unsigned short)a.y) + b2f((unsigned short)b.y);
      float v3 = b2f((unsigned short)(a.y >> 16)) + b2f((unsigned short)(b.y >> 16));
      v0 = fmaf(v0, ss[k], ss[256 + k]);         v0 = v0 > 0.f ? v0 : 0.f;
      v1 = fmaf(v1, ss[k + 1], ss[257 + k]);     v1 = v1 > 0.f ? v1 : 0.f;
      v2 = fmaf(v2, ss[k + 2], ss[258 + k]);     v2 = v2 > 0.f ? v2 : 0.f;
      v3 = fmaf(v3, ss[k + 3], ss[259 + k]);     v3 = v3 > 0.f ? v3 : 0.f;
      uint2 pk;
      pk.x = (unsigned int)f2b(v0) | ((unsigned int)f2b(v1) << 16);
      pk.y = (unsigned int)f2b(v2) | ((unsigned int)f2b(v3) << 16);
      *(uint2*)&As[r][seg * 4] = pk;
    }
#pragma unroll
    for (int e = t; e < 512; e += 256) {
      int nn = e >> 2, c = e & 3;
      *(int4*)&Ws[nn][c * 8] = *(const int4*)(W + (size_t)nn * 256 + k0 + c * 8);
    }
    __syncthreads();
    bfrag b0 = *(const bfrag*)&Ws[colbase + m16][kq * 8];
    bfrag b1 = *(const bfrag*)&Ws[colbase + 16 + m16][kq * 8];
#pragma unroll
    for (int rb = 0; rb < 4; ++rb) {
      bfrag a = *(const bfrag*)&As[rb * 16 + m16][kq * 8];
      acc[rb][0] = __builtin_amdgcn_mfma_f32_16x16x32_bf16(a, b0, acc[rb][0], 0, 0, 0);
      acc[rb][1] = __builtin_amdgcn_mfma_f32_16x16x32_bf16(a, b1, acc[rb][1], 0, 0, 0);
    }
  }
#pragma unroll
  for (int rb = 0; rb < 4; ++rb)
#pragma unroll
    for (int cb = 0; cb < 2; ++cb) {
      int col = colbase + cb * 16 + m16;
      float bv = bias[col];
#pragma unroll
      for (int r = 0; r < 4; ++r) {
        int row = row0 + rb * 16 + kq * 4 + r;
        if (row < n) Co[(size_t)row * 128 + col] = f2b(acc[rb][cb][r] + bv);
      }
    }
}

// wave-per-row column stats for bf16 matrix Z[B][C], C in {128, 64}
template<int C>
__global__ void k_bnst(const unsigned short* __restrict__ Z, int B, double* __restrict__ st) {
  constexpr int CPL = C / 64;
  __shared__ double sS[4][C];
  __shared__ double sQ[4][C];
  const int t = threadIdx.x;
  const int lane = t & 63, w = t >> 6;
  double s[CPL] = {}, q[CPL] = {};
  const int NW = gridDim.x * 4;
  for (int r = blockIdx.x * 4 + w; r < B; r += NW) {
    if (CPL == 2) {
      unsigned int u = *(const unsigned int*)(Z + (size_t)r * C + lane * 2);
      float v0 = b2f((unsigned short)u);
      float v1 = b2f((unsigned short)(u >> 16));
      s[0] += v0; q[0] += (double)v0 * (double)v0;
      s[1] += v1; q[1] += (double)v1 * (double)v1;
    } else {
      float v0 = b2f(Z[(size_t)r * C + lane]);
      s[0] += v0; q[0] += (double)v0 * (double)v0;
    }
  }
#pragma unroll
  for (int k = 0; k < CPL; ++k) { sS[w][lane * CPL + k] = s[k]; sQ[w][lane * CPL + k] = q[k]; }
  __syncthreads();
  if (t < C) {
    double ts = sS[0][t] + sS[1][t] + sS[2][t] + sS[3][t];
    double tq = sQ[0][t] + sQ[1][t] + sQ[2][t] + sQ[3][t];
    atomicAdd(&st[t], ts);
    atomicAdd(&st[C + t], tq);
  }
}

__global__ void k_bnfin(const double* __restrict__ st, int B, int C,
                        const float* __restrict__ g, const float* __restrict__ be,
                        float* __restrict__ ss) {
  int c = threadIdx.x;
  if (c < C) {
    double m = st[c] / B;
    double v = st[C + c] / B - m * m;
    if (v < 0) v = 0;
    float sc = (float)((double)g[c] / sqrt(v + 1e-5));
    ss[c] = sc;
    ss[C + c] = be[c] - (float)m * sc;
  }
}

__global__ void k_final(const unsigned short* __restrict__ Z3, const float* __restrict__ ss3,
                        const float* __restrict__ Wo, const float* __restrict__ bo,
                        void* __restrict__ out, int B, const int* __restrict__ flagp) {
  __shared__ float w[64], sc[64], sh[64];
  if (threadIdx.x < 64) {
    w[threadIdx.x] = Wo[threadIdx.x];
    sc[threadIdx.x] = ss3[threadIdx.x];
    sh[threadIdx.x] = ss3[64 + threadIdx.x];
  }
  __syncthreads();
  const int bf = *flagp;
  const float bb = bo[0];
  for (int r = blockIdx.x * blockDim.x + threadIdx.x; r < B; r += gridDim.x * blockDim.x) {
    const unsigned short* z = &Z3[(size_t)r * 64];
    float acc = bb;
#pragma unroll
    for (int k = 0; k < 64; ++k) {
      float y = fmaf(b2f(z[k]), sc[k], sh[k]);
      y = y > 0.f ? y : 0.f;
      acc = fmaf(y, w[k], acc);
    }
    float sv = 1.f / (1.f + expf(-acc));
    if (bf) ((unsigned short*)out)[r] = f2b(sv);
    else ((float*)out)[r] = sv;
  }
}

extern "C" void kernel_launch(void* const* d_in, const int* in_sizes, int n_in,
                              void* d_out, int out_size, void* d_ws, size_t ws_size,
                              hipStream_t stream) {
  enum { N_DR = 8000, N_P = 20000, N_DIS = 5000, N_MF = 3000, N_BP = 8000,
         N_CC = 2000, N_PATH = 2392 };
  if (n_in < 59) return;
  const int B = in_sizes[0];
  const int* x_dr = (const int*)d_in[0];
  const int* x_p  = (const int*)d_in[1];

  char* base = (char*)d_ws;
  size_t off = 0;
  auto alloc = [&](size_t bytes) -> void* {
    void* p = base + off;
    off += (bytes + 255) & ~(size_t)255;
    return p;
  };
  int*    flagp = (int*)alloc(256);
  double* st1 = (double*)alloc(896 * sizeof(double));
  double* st2 = st1 + 512; double* st3 = st2 + 256;
  float*  ss1 = (float*)alloc(896 * sizeof(float));
  float*  ss2 = ss1 + 512; float* ss3 = ss2 + 256;
  float*  pbuf = (float*)alloc(6000 * sizeof(float));
  unsigned short* wbf = (unsigned short*)alloc(1100000 * 2);
  unsigned short* DR  = (unsigned short*)alloc((size_t)N_DR * 384 * 2);
  unsigned short* P   = (unsigned short*)alloc((size_t)N_P * 512 * 2);
  unsigned short* h_d = (unsigned short*)alloc((size_t)N_DIS * 128 * 2);
  unsigned short* d1b = (unsigned short*)alloc((size_t)N_DIS * 128 * 2);
  unsigned short* z1  = (unsigned short*)alloc((size_t)B * 256 * 2);
  char* arena = (char*)alloc(44u * 1024 * 1024);
  if (off > ws_size) return;

  unsigned short* ar = (unsigned short*)arena;
  unsigned short* A_hmf  = ar;
  unsigned short* A_hbp  = A_hmf + (size_t)N_MF * 128;
  unsigned short* A_hcc  = A_hbp + (size_t)N_BP * 128;
  unsigned short* A_hpath= A_hcc + (size_t)N_CC * 128;
  unsigned short* A_gomf = A_hpath + (size_t)N_PATH * 128;
  unsigned short* A_gobp = A_gomf + (size_t)N_MF * 128;
  unsigned short* A_gocc = A_gobp + (size_t)N_BP * 128;
  unsigned short* ag17 = A_gocc + (size_t)N_CC * 128;
  unsigned short* ag18 = ag17 + (size_t)N_MF * 128;
  unsigned short* ag19 = ag18 + (size_t)N_BP * 128;
  unsigned short* ag20 = ag19 + (size_t)N_CC * 128;
  unsigned short* ag21 = ag20 + (size_t)N_P * 128;
  unsigned short* ag22 = ag21 + (size_t)N_P * 128;
  unsigned short* ag23 = ag22 + (size_t)N_P * 128;
  unsigned short* pl0 = ar;
  unsigned short* pl1 = pl0 + (size_t)N_DIS * 128;
  unsigned short* pl2 = pl1 + (size_t)N_DIS * 128;
  unsigned short* pl3 = pl2 + (size_t)N_DIS * 128;
  unsigned short* pl4 = pl3 + (size_t)N_DR * 128;
  unsigned short* pl5 = pl4 + (size_t)N_DR * 128;
  unsigned short* pl6 = pl5 + (size_t)N_P * 128;
  unsigned short* pl7 = pl6 + (size_t)N_DR * 128;
  unsigned short* ag9  = pl7 + (size_t)N_P * 128;
  unsigned short* ag10 = ag9 + (size_t)N_DR * 128;
  unsigned short* ag11 = ag10 + (size_t)N_DR * 128;
  unsigned short* ag12 = ag11 + (size_t)N_P * 128;
  unsigned short* ag13 = ag12 + (size_t)N_DIS * 128;
  unsigned short* ag14 = ag13 + (size_t)N_DIS * 128;
  unsigned short* ag15 = ag14 + (size_t)N_DIS * 128;
  unsigned short* ag16 = ag15 + (size_t)N_DR * 128;
  unsigned short* U_dr = ar;
  unsigned short* U_p  = U_dr + (size_t)N_DR * 256;
  unsigned short* z2 = U_p + (size_t)N_P * 256;
  unsigned short* z3 = z1;
  int* slot_arena = (int*)arena;

  k_flag<<<1, 64, 0, stream>>>((const unsigned int*)d_in[5], flagp);

  float* pp[59] = {};
  {
    PArgs pa;
    const int pidx[NPT] = {25,27,29,31,33,35,37,39,41,44,46,47,48,50,51,52,54,55,56,57,58};
    size_t poff = 0;
    for (int l = 0; l < NPT; ++l) {
      int i = pidx[l];
      pa.t[l].src = d_in[i]; pa.t[l].dst = pbuf + poff; pa.t[l].n = in_sizes[i]; pa.t[l].pad = 0;
      pp[i] = pbuf + poff;
      poff += in_sizes[i];
    }
    k_cv_params<<<dim3(4, NPT), 256, 0, stream>>>(pa, flagp);
  }

  unsigned short *Wdr_t, *Wpe_t, *Wde_t, *Wg_t, *Wps_t, *Wss_t, *Wns_t, *W1_t, *W2_t, *W3_t;
  {
    WArgs wa;
    int l = 0; size_t woff = 0;
    auto add = [&](int inIdx, int eoff, int K, int N) -> unsigned short* {
      unsigned short* dst = wbf + woff;
      wa.t[l].src = d_in[inIdx]; wa.t[l].dst = dst; wa.t[l].K = K; wa.t[l].N = N;
      wa.t[l].eoff = eoff; wa.t[l].pad = 0;
      ++l; woff += (size_t)K * N;
      return dst;
    };
    Wdr_t = add(24, 0, 1024, 128);
    Wpe_t = add(26, 0, 400, 128);
    Wde_t = add(28, 0, 512, 128);
    Wg_t = wbf + woff;
    for (int j = 0; j < 7; ++j) add(38, j * 16384, 128, 128);
    Wps_t = wbf + woff;
    for (int j = 0; j < 8; ++j) add(40, j * 16384, 128, 128);
    Wss_t = wbf + woff;
    for (int j = 0; j < 8; ++j) add(42, j * 16384, 128, 128);
    Wns_t = wbf + woff;
    for (int j = 0; j < 8; ++j) add(43, j * 16384, 128, 128);
    W1_t = add(45, 0, 896, 256);
    W2_t = add(49, 0, 256, 128);
    W3_t = add(53, 0, 128, 64);
    k_cv_wt<<<dim3(32, NWT), 256, 0, stream>>>(wa, flagp);
  }

  const int list_ei[NCSR] = {9, 10, 11, 12, 13, 14, 15, 16, 17, 18, 19, 20, 21, 22, 23};
  const int list_nd[NCSR] = {N_DR, N_DR, N_P, N_DIS, N_DIS, N_DIS, N_DR, N_P,
                             N_MF, N_BP, N_CC, N_P, N_P, N_P, N_P};
  int* rp[24]; unsigned short* cs[24];
  CsrArgs csra;
  {
    int* ip = (int*)z1;
    int* rp0 = ip;
    for (int l = 0; l < NCSR; ++l) { csra.d[l].rowptr = ip; rp[list_ei[l]] = ip; ip += list_nd[l] + 1; }
    size_t rp_total = (size_t)(ip - rp0);
    unsigned short* up = (unsigned short*)ip;
    size_t slotoff = 0;
    for (int l = 0; l < NCSR; ++l) {
      int ei = list_ei[l];
      int E = in_sizes[ei] / 2;
      csra.d[l].src = (const int*)d_in[ei];
      csra.d[l].dst = (const int*)d_in[ei] + E;
      csra.d[l].E = E;
      csra.d[l].n_dst = list_nd[l];
      csra.d[l].csrc = up; cs[ei] = up;
      csra.d[l].slot = slot_arena + slotoff;
      csra.d[l].pad = 0;
      up += E;
      slotoff += E;
    }
    hipMemsetAsync(rp0, 0, rp_total * sizeof(int), stream);
  }
  k_csr_count<<<dim3(96, NCSR), 256, 0, stream>>>(csra);
  k_csr_scan<<<NCSR, 1024, 0, stream>>>(csra);
  k_csr_fill<<<dim3(96, NCSR), 256, 0, stream>>>(csra);

  hipMemsetAsync(st1, 0, 896 * sizeof(double), stream);

  {
    EArgs ea;
    ea.t[0] = {d_in[2], Wdr_t, pp[25], DR, N_DR, 1024, 384, 0};
    ea.t[1] = {d_in[3], Wpe_t, pp[27], P, N_P, 400, 512, 0};
    ea.t[2] = {d_in[4], Wde_t, pp[29], h_d, N_DIS, 512, 128, 0};
    k_embed_multi<<<dim3((N_P + 31) / 32, 3), 256, 0, stream>>>(ea, flagp);
  }
  {
    BArgs ba;
    ba.t[0] = {d_in[30], pp[31], A_hmf, N_MF * 128, {}};
    ba.t[1] = {d_in[32], pp[33], A_hbp, N_BP * 128, {}};
    ba.t[2] = {d_in[34], pp[35], A_hcc, N_CC * 128, {}};
    ba.t[3] = {d_in[36], pp[37], A_hpath, N_PATH * 128, {}};
    k_biasrelu_multi<<<dim3(128, 4), 256, 0, stream>>>(ba, flagp);
  }

  auto mkpass = [](MTask& T, int i, const unsigned short* A, int lda, const unsigned short* W,
                   int ldw, const float* bias, int end) {
    T.p[i].A = A; T.p[i].lda = lda; T.p[i].W = W; T.p[i].ldw = ldw;
    T.p[i].bias = bias; T.p[i].flags = end;
  };
  const float* bg = pp[39];
  const float* bp_s = pp[41];
  const float* b_s = pp[44];

  {
    GArgs ga;
    ga.t[0] = {rp[17], cs[17], A_hmf, ag17, N_MF, 128, 0, 0};
    ga.t[1] = {rp[18], cs[18], A_hbp, ag18, N_BP, 128, 0, 0};
    ga.t[2] = {rp[19], cs[19], A_hcc, ag19, N_CC, 128, 0, 0};
    k_gather_multi<<<dim3((N_BP + 3) / 4, 3), 256, 0, stream>>>(ga);
  }
  {
    MArgs ma;
    for (int i = 0; i < 3; ++i) {
      MTask& T = ma.t[i];
      const unsigned short* aggp = (i == 0) ? ag17 : (i == 1) ? ag18 : ag19;
      const unsigned short* Rp = (i == 0) ? A_hmf : (i == 1) ? A_hbp : A_hcc;
      unsigned short* Cp = (i == 0) ? A_gomf : (i == 1) ? A_gobp : A_gocc;
      int n = (i == 0) ? N_MF : (i == 1) ? N_BP : N_CC;
      mkpass(T, 0, aggp, 128, Wg_t + (size_t)i * 16384, 128, bg + i * 128, 1);
      T.npass = 1; T.n = n; T.K = 128; T.R = Rp; T.C = Cp; T.ldc = 128; T.relu = 1;
    }
    k_mg<<<dim3((N_BP + 63) / 64, 3), 256, 0, stream>>>(ma);
  }
  {
    GArgs ga;
    ga.t[0] = {rp[20], cs[20], A_gomf, ag20, N_P, 128, 0, 0};
    ga.t[1] = {rp[21], cs[21], A_gobp, ag21, N_P, 128, 0, 0};
    ga.t[2] = {rp[22], cs[22], A_gocc, ag22, N_P, 128, 0, 0};
    ga.t[3] = {rp[23], cs[23], A_hpath, ag23, N_P, 128, 0, 0};
    k_gather_multi<<<dim3((N_P + 3) / 4, 4), 256, 0, stream>>>(ga);
  }
  {
    MArgs ma;
    MTask& T = ma.t[0];
    mkpass(T, 0, ag20, 128, Wg_t + 3 * 16384, 128, bg + 3 * 128, 1);
    mkpass(T, 1, ag21, 128, Wg_t + 4 * 16384, 128, bg + 4 * 128, 1);
    mkpass(T, 2, ag22, 128, Wg_t + 5 * 16384, 128, bg + 5 * 128, 1);
    mkpass(T, 3, ag23, 128, Wg_t + 6 * 16384, 128, bg + 6 * 128, 1);
    T.npass = 4; T.n = N_P; T.K = 128; T.R = nullptr; T.C = P + 384; T.ldc = 512; T.relu = 1;
    k_mg<<<dim3((N_P + 63) / 64, 1), 256, 0, stream>>>(ma);
  }

  {
    MArgs ma;
    const unsigned short* xs[8] = {h_d, h_d, h_d, DR, DR, P, DR, P};
    const int lda[8] = {128, 128, 128, 384, 384, 512, 384, 512};
    const int nn[8] = {N_DIS, N_DIS, N_DIS, N_DR, N_DR, N_P, N_DR, N_P};
    unsigned short* plo[8] = {pl0, pl1, pl2, pl3, pl4, pl5, pl6, pl7};
    for (int i = 0; i < 8; ++i) {
      MTask& T = ma.t[i];
      mkpass(T, 0, xs[i], lda[i], Wps_t + (size_t)i * 16384, 128, bp_s + i * 128, 1);
      T.npass = 1; T.n = nn[i]; T.K = 128; T.R = nullptr; T.C = plo[i]; T.ldc = 128; T.relu = 1;
    }
    k_mg<<<dim3((N_P + 63) / 64, 8), 256, 0, stream>>>(ma);
  }
  {
    GArgs ga;
    ga.t[0] = {rp[9],  cs[9],  pl0, ag9,  N_DR, 128, 1, 0};
    ga.t[1] = {rp[10], cs[10], pl1, ag10, N_DR, 128, 1, 0};
    ga.t[2] = {rp[11], cs[11], pl2, ag11, N_P, 128, 1, 0};
    ga.t[3] = {rp[12], cs[12], pl3, ag12, N_DIS, 128, 1, 0};
    ga.t[4] = {rp[13], cs[13], pl4, ag13, N_DIS, 128, 1, 0};
    ga.t[5] = {rp[14], cs[14], pl5, ag14, N_DIS, 128, 1, 0};
    ga.t[6] = {rp[15], cs[15], pl6, ag15, N_DR, 128, 1, 0};
    ga.t[7] = {rp[16], cs[16], pl7, ag16, N_P, 128, 1, 0};
    k_gather_multi<<<dim3((N_P + 3) / 4, 8), 256, 0, stream>>>(ga);
  }
  {
    MArgs ma;
    {
      MTask& T = ma.t[0];
      mkpass(T, 0, DR, 384, Wss_t + (size_t)0 * 16384, 128, nullptr, 0);
      mkpass(T, 1, ag9, 128, Wns_t + (size_t)0 * 16384, 128, b_s + 0 * 128, 1);
      mkpass(T, 2, DR, 384, Wss_t + (size_t)1 * 16384, 128, nullptr, 0);
      mkpass(T, 3, ag10, 128, Wns_t + (size_t)1 * 16384, 128, b_s + 1 * 128, 1);
      mkpass(T, 4, DR, 384, Wss_t + (size_t)6 * 16384, 128, nullptr, 0);
      mkpass(T, 5, ag15, 128, Wns_t + (size_t)6 * 16384, 128, b_s + 6 * 128, 1);
      T.npass = 6; T.n = N_DR; T.K = 128; T.R = nullptr; T.C = DR + 128; T.ldc = 384; T.relu = 1;
    }
    {
      MTask& T = ma.t[1];
      mkpass(T, 0, P, 512, Wss_t + (size_t)2 * 16384, 128, nullptr, 0);
      mkpass(T, 1, ag11, 128, Wns_t + (size_t)2 * 16384, 128, b_s + 2 * 128, 1);
      mkpass(T, 2, P, 512, Wss_t + (size_t)7 * 16384, 128, nullptr, 0);
      mkpass(T, 3, ag16, 128, Wns_t + (size_t)7 * 16384, 128, b_s + 7 * 128, 1);
      T.npass = 4; T.n = N_P; T.K = 128; T.R = nullptr; T.C = P + 128; T.ldc = 512; T.relu = 1;
    }
    {
      MTask& T = ma.t[2];
      mkpass(T, 0, h_d, 128, Wss_t + (size_t)3 * 16384, 128, nullptr, 0);
      mkpass(T, 1, ag12, 128, Wns_t + (size_t)3 * 16384, 128, b_s + 3 * 128, 1);
      mkpass(T, 2, h_d, 128, Wss_t + (size_t)4 * 16384, 128, nullptr, 0);
      mkpass(T, 3, ag13, 128, Wns_t + (size_t)4 * 16384, 128, b_s + 4 * 128, 1);
      mkpass(T, 4, h_d, 128, Wss_t + (size_t)5 * 16384, 128, nullptr, 0);
      mkpass(T, 5, ag14, 128, Wns_t + (size_t)5 * 16384, 128, b_s + 5 * 128, 1);
      T.npass = 6; T.n = N_DIS; T.K = 128; T.R = nullptr; T.C = d1b; T.ldc = 128; T.relu = 1;
    }
    k_mg<<<dim3((N_P + 63) / 64, 3), 256, 0, stream>>>(ma);
  }

  {
    MArgs ma;
    const unsigned short* xs[5] = {d1b, d1b, d1b, DR + 128, P + 128};
    const int lda[5] = {128, 128, 128, 384, 512};
    const int nn[5] = {N_DIS, N_DIS, N_DIS, N_DR, N_P};
    unsigned short* plo[5] = {pl0, pl1, pl2, pl6, pl7};
    const int si[5] = {0, 1, 2, 6, 7};
    for (int i = 0; i < 5; ++i) {
      MTask& T = ma.t[i];
      mkpass(T, 0, xs[i], lda[i], Wps_t + (size_t)si[i] * 16384, 128, bp_s + si[i] * 128, 1);
      T.npass = 1; T.n = nn[i]; T.K = 128; T.R = nullptr; T.C = plo[i]; T.ldc = 128; T.relu = 1;
    }
    k_mg<<<dim3((N_P + 63) / 64, 5), 256, 0, stream>>>(ma);
  }
  {
    GArgs ga;
    ga.t[0] = {rp[9],  cs[9],  pl0, ag9,  N_DR, 128, 1, 0};
    ga.t[1] = {rp[10], cs[10], pl1, ag10, N_DR, 128, 1, 0};
    ga.t[2] = {rp[11], cs[11], pl2, ag11, N_P, 128, 1, 0};
    ga.t[3] = {rp[15], cs[15], pl6, ag15, N_DR, 128, 1, 0};
    ga.t[4] = {rp[16], cs[16], pl7, ag16, N_P, 128, 1, 0};
    k_gather_multi<<<dim3((N_P + 3) / 4, 5), 256, 0, stream>>>(ga);
  }
  {
    MArgs ma;
    {
      MTask& T = ma.t[0];
      mkpass(T, 0, DR + 128, 384, Wss_t + (size_t)0 * 16384, 128, nullptr, 0);
      mkpass(T, 1, ag9, 128, Wns_t + (size_t)0 * 16384, 128, b_s + 0 * 128, 1);
      mkpass(T, 2, DR + 128, 384, Wss_t + (size_t)1 * 16384, 128, nullptr, 0);
      mkpass(T, 3, ag10, 128, Wns_t + (size_t)1 * 16384, 128, b_s + 1 * 128, 1);
      mkpass(T, 4, DR + 128, 384, Wss_t + (size_t)6 * 16384, 128, nullptr, 0);
      mkpass(T, 5, ag15, 128, Wns_t + (size_t)6 * 16384, 128, b_s + 6 * 128, 1);
      T.npass = 6; T.n = N_DR; T.K = 128; T.R = nullptr; T.C = DR + 256; T.ldc = 384; T.relu = 1;
    }
    {
      MTask& T = ma.t[1];
      mkpass(T, 0, P + 128, 512, Wss_t + (size_t)2 * 16384, 128, nullptr, 0);
      mkpass(T, 1, ag11, 128, Wns_t + (size_t)2 * 16384, 128, b_s + 2 * 128, 1);
      mkpass(T, 2, P + 128, 512, Wss_t + (size_t)7 * 16384, 128, nullptr, 0);
      mkpass(T, 3, ag16, 128, Wns_t + (size_t)7 * 16384, 128, b_s + 7 * 128, 1);
      T.npass = 4; T.n = N_P; T.K = 128; T.R = nullptr; T.C = P + 256; T.ldc = 512; T.relu = 1;
    }
    k_mg<<<dim3((N_P + 63) / 64, 2), 256, 0, stream>>>(ma);
  }

  {
    MArgs ma;
    for (int half = 0; half < 2; ++half) {
      {
        MTask& T = ma.t[half];
        mkpass(T, 0, DR, 384, W1_t + (size_t)(half * 128) * 896, 896, pp[46] + half * 128, 1);
        T.npass = 1; T.n = N_DR; T.K = 384; T.R = nullptr;
        T.C = U_dr + half * 128; T.ldc = 256; T.relu = 0;
      }
      {
        MTask& T = ma.t[2 + half];
        mkpass(T, 0, P, 512, W1_t + (size_t)(half * 128) * 896 + 384, 896, nullptr, 1);
        T.npass = 1; T.n = N_P; T.K = 512; T.R = nullptr;
        T.C = U_p + half * 128; T.ldc = 256; T.relu = 0;
      }
    }
    k_mg<<<dim3((N_P + 63) / 64, 4), 256, 0, stream>>>(ma);
  }

  k_hstat<<<256, 256, 0, stream>>>(x_dr, x_p, U_dr, U_p, st1, B);
  k_bnfin<<<1, 256, 0, stream>>>(st1, B, 256, pp[47], pp[48], ss1);

  k_gemm_bn1<<<(B + 63) / 64, 256, 0, stream>>>(x_dr, x_p, U_dr, U_p, W2_t, pp[50], ss1, z2, B);
  k_bnst<128><<<256, 256, 0, stream>>>(z2, B, st2);
  k_bnfin<<<1, 128, 0, stream>>>(st2, B, 128, pp[51], pp[52], ss2);

  k_gemm_bn<64><<<(B + 63) / 64, 256, 0, stream>>>(z2, W3_t, pp[54], ss2, z3, B, 128);
  k_bnst<64><<<256, 256, 0, stream>>>(z3, B, st3);
  k_bnfin<<<1, 64, 0, stream>>>(st3, B, 64, pp[55], pp[56], ss3);

  k_final<<<256, 256, 0, stream>>>(z3, ss3, pp[57], pp[58], d_out, B, flagp);
}